// Round 11
// baseline (485.593 us; speedup 1.0000x reference)
//
#include <hip/hip_runtime.h>
#include <math.h>

typedef unsigned short u16;
typedef __attribute__((ext_vector_type(8))) short short8v;  // 8 bf16 operand frag
typedef __attribute__((ext_vector_type(4))) float f32x4;    // MFMA accumulator

constexpr int B  = 2;
constexpr int N  = 2048;
constexpr int C  = 1024;
constexpr int H  = 16;
constexpr int DK = 64;
constexpr int NTOP = 512;
constexpr float SCALE = 0.125f;  // 1/sqrt(64)
constexpr int   BAND_CAP = 1024;
constexpr float BAND_EPS = 2e-3f;   // covers 3-term split-bf16 M error (~1e-4)
constexpr int   CSEG = 16;          // column-sum segments per bh

// ---------------------------------------------------------------------------
// async global -> LDS, 16B per lane. (verified r8)
// ---------------------------------------------------------------------------
__device__ __forceinline__ void gload16(const u16* g, u16* l) {
    __builtin_amdgcn_global_load_lds(
        (const __attribute__((address_space(1))) unsigned int*)g,
        (__attribute__((address_space(3))) unsigned int*)l,
        16, 0, 0);
}

// ---------------------------------------------------------------------------
// fp32 -> bf16 hi/lo split (RNE)
// ---------------------------------------------------------------------------
__device__ __forceinline__ u16 bf16_rne(float x) {
    unsigned u = __float_as_uint(x);
    unsigned r = u + 0x7fffu + ((u >> 16) & 1u);
    return (u16)(r >> 16);
}

__global__ __launch_bounds__(256) void convert_hilo(
    const float* __restrict__ src, u16* __restrict__ hi, u16* __restrict__ lo, int n)
{
    int i = (blockIdx.x * 256 + threadIdx.x) * 4;
    if (i >= n) return;
    float4 v = *(const float4*)&src[i];
    u16 h0 = bf16_rne(v.x), h1 = bf16_rne(v.y), h2 = bf16_rne(v.z), h3 = bf16_rne(v.w);
    float f0 = __uint_as_float((unsigned)h0 << 16);
    float f1 = __uint_as_float((unsigned)h1 << 16);
    float f2 = __uint_as_float((unsigned)h2 << 16);
    float f3 = __uint_as_float((unsigned)h3 << 16);
    *(ushort4*)&hi[i] = make_ushort4(h0, h1, h2, h3);
    *(ushort4*)&lo[i] = make_ushort4(bf16_rne(v.x - f0), bf16_rne(v.y - f1),
                                     bf16_rne(v.z - f2), bf16_rne(v.w - f3));
}

// two-source variant (q and k in one launch); grid (n/1024, 2)
__global__ __launch_bounds__(256) void convert_hilo2(
    const float* __restrict__ a, const float* __restrict__ b,
    u16* __restrict__ ah, u16* __restrict__ al,
    u16* __restrict__ bh_, u16* __restrict__ bl_, int n)
{
    const float* src = blockIdx.y ? b : a;
    u16* hi = blockIdx.y ? bh_ : ah;
    u16* lo = blockIdx.y ? bl_ : al;
    int i = (blockIdx.x * 256 + threadIdx.x) * 4;
    if (i >= n) return;
    float4 v = *(const float4*)&src[i];
    u16 h0 = bf16_rne(v.x), h1 = bf16_rne(v.y), h2 = bf16_rne(v.z), h3 = bf16_rne(v.w);
    float f0 = __uint_as_float((unsigned)h0 << 16);
    float f1 = __uint_as_float((unsigned)h1 << 16);
    float f2 = __uint_as_float((unsigned)h2 << 16);
    float f3 = __uint_as_float((unsigned)h3 << 16);
    *(ushort4*)&hi[i] = make_ushort4(h0, h1, h2, h3);
    *(ushort4*)&lo[i] = make_ushort4(bf16_rne(v.x - f0), bf16_rne(v.y - f1),
                                     bf16_rne(v.z - f2), bf16_rne(v.w - f3));
}

// ---------------------------------------------------------------------------
// Transposed convert: v (bh, key, d) fp32 -> vt hi/lo (bh, d, key) bf16. (r6)
// ---------------------------------------------------------------------------
__global__ __launch_bounds__(256) void convert_hilo_T(
    const float* __restrict__ v, u16* __restrict__ th, u16* __restrict__ tl)
{
    constexpr int LS = 68;
    __shared__ u16 Sh[64 * LS], Sl[64 * LS];
    const int bh = blockIdx.y;
    const int kt = blockIdx.x * 64;
    const int tid = threadIdx.x;
    #pragma unroll
    for (int p = 0; p < 4; ++p) {
        int idx = tid * 4 + p * 1024;
        int key = idx >> 6, d = idx & 63;
        float4 x4 = *(const float4*)&v[((size_t)bh * N + kt + key) * DK + d];
        float xs[4] = {x4.x, x4.y, x4.z, x4.w};
        ushort4 hh, ll;
        u16* hp = (u16*)&hh; u16* lp = (u16*)&ll;
        #pragma unroll
        for (int j = 0; j < 4; ++j) {
            u16 h = bf16_rne(xs[j]);
            hp[j] = h;
            lp[j] = bf16_rne(xs[j] - __uint_as_float((unsigned)h << 16));
        }
        *(ushort4*)&Sh[key * LS + d] = hh;
        *(ushort4*)&Sl[key * LS + d] = ll;
    }
    __syncthreads();
    const int d = tid >> 2, seg = tid & 3;
    u16 bufh[16], bufl[16];
    #pragma unroll
    for (int i = 0; i < 16; ++i) {
        bufh[i] = Sh[(seg * 16 + i) * LS + d];
        bufl[i] = Sl[(seg * 16 + i) * LS + d];
    }
    size_t oa = ((size_t)bh * DK + d) * N + kt + seg * 16;
    *(uint4*)&th[oa] = ((uint4*)bufh)[0];
    *(uint4*)&th[oa + 8] = ((uint4*)bufh)[1];
    *(uint4*)&tl[oa] = ((uint4*)bufl)[0];
    *(uint4*)&tl[oa + 8] = ((uint4*)bufl)[1];
}

// ---------------------------------------------------------------------------
// Split-bf16 MFMA GEMM: 128x128 tile, BK=32, 4 waves, gload staging.
// 2D grid (r9-verified config — no swizzle).
// ---------------------------------------------------------------------------
template <int MODE>
__global__ __launch_bounds__(256) void gemm_mfma(
    const u16* __restrict__ Ahi, const u16* __restrict__ Alo,
    const u16* __restrict__ Bhi, const u16* __restrict__ Blo,
    const float* __restrict__ bias, float* __restrict__ out,
    float* __restrict__ qb, float* __restrict__ kb, float* __restrict__ vb,
    int K)
{
    __shared__ __align__(16) u16 Ah[128 * 32], Al[128 * 32];
    __shared__ __align__(16) u16 Bh[128 * 32], Bl[128 * 32];

    const int tid = threadIdx.x;
    const int m0 = blockIdx.y * 128;
    const int n0 = blockIdx.x * 128;
    const int lane = tid & 63;
    const int wave = tid >> 6;
    const int wr = wave >> 1, wc = wave & 1;
    const int fr = lane & 15, sl = lane >> 4;

    const u16* gsrc = (wave == 0) ? Ahi + (size_t)m0 * K
                    : (wave == 1) ? Alo + (size_t)m0 * K
                    : (wave == 2) ? Bhi + (size_t)n0 * K
                                  : Blo + (size_t)n0 * K;
    u16* lbase = (wave == 0) ? Ah : (wave == 1) ? Al : (wave == 2) ? Bh : Bl;

    f32x4 acc[4][4] = {};

    for (int k0 = 0; k0 < K; k0 += 32) {
        __syncthreads();
        #pragma unroll
        for (int i = 0; i < 8; ++i) {
            int c = i * 64 + lane;               // chunk = 16B = 8 u16
            int row = c >> 2, sp = c & 3;
            int gs = sp ^ ((row >> 1) & 3);
            gload16(gsrc + (size_t)row * K + k0 + gs * 8, lbase + i * 512);
        }
        __syncthreads();

        short8v afh[4], afl[4], bfh[4], bfl[4];
        #pragma unroll
        for (int m = 0; m < 4; ++m) {
            int row = wr * 64 + m * 16 + fr;
            int off = row * 32 + ((sl ^ ((row >> 1) & 3)) * 8);
            afh[m] = *(const short8v*)&Ah[off];
            afl[m] = *(const short8v*)&Al[off];
        }
        #pragma unroll
        for (int n = 0; n < 4; ++n) {
            int row = wc * 64 + n * 16 + fr;
            int off = row * 32 + ((sl ^ ((row >> 1) & 3)) * 8);
            bfh[n] = *(const short8v*)&Bh[off];
            bfl[n] = *(const short8v*)&Bl[off];
        }
        #pragma unroll
        for (int m = 0; m < 4; ++m)
            #pragma unroll
            for (int n = 0; n < 4; ++n) {
                acc[m][n] = __builtin_amdgcn_mfma_f32_16x16x32_bf16(afh[m], bfh[n], acc[m][n], 0, 0, 0);
                acc[m][n] = __builtin_amdgcn_mfma_f32_16x16x32_bf16(afh[m], bfl[n], acc[m][n], 0, 0, 0);
                acc[m][n] = __builtin_amdgcn_mfma_f32_16x16x32_bf16(afl[m], bfh[n], acc[m][n], 0, 0, 0);
            }
    }

    #pragma unroll
    for (int m = 0; m < 4; ++m)
        #pragma unroll
        for (int n = 0; n < 4; ++n)
            #pragma unroll
            for (int r = 0; r < 4; ++r) {
                int grow = m0 + wr * 64 + m * 16 + sl * 4 + r;
                int gcol = n0 + wc * 64 + n * 16 + fr;
                float val = acc[m][n][r] + bias[gcol];
                if (MODE == 0) {
                    int t = gcol >> 10, h = (gcol >> 6) & 15, d = gcol & 63;
                    int bb = grow >> 11, nn = grow & (N - 1);
                    float* dst = (t == 0) ? qb : (t == 1) ? kb : vb;
                    dst[(((size_t)bb * H + h) * N + nn) * DK + d] = val;
                } else {
                    out[(size_t)grow * C + gcol] = val;
                }
            }
}

// ---------------------------------------------------------------------------
// Column sums over v and k in one launch.  grid (CSEG, B*H, 2), z: 0=v 1=k.
// ---------------------------------------------------------------------------
__global__ __launch_bounds__(256) void colsum_part2(
    const float* __restrict__ v, const float* __restrict__ k,
    float* __restrict__ partial)
{
    const int bh = blockIdx.y, seg = blockIdx.x, which = blockIdx.z;
    const float* src = which ? k : v;
    const int d = threadIdx.x & 63;
    const int sub = threadIdx.x >> 6;
    const int k0 = seg * (N / CSEG);
    float s = 0.f;
    for (int kk = sub; kk < N / CSEG; kk += 4)
        s += src[((size_t)bh * N + k0 + kk) * DK + d];
    __shared__ float part[4][64];
    part[sub][d] = s;
    __syncthreads();
    if (threadIdx.x < 64)
        partial[(((size_t)which * B * H + bh) * CSEG + seg) * DK + d] =
            part[0][d] + part[1][d] + part[2][d] + part[3][d];
}

// grid (B*H), 128 threads: tid<64 -> vmean, tid>=64 -> kmean
__global__ __launch_bounds__(128) void colsum_final2(
    const float* __restrict__ partial, float* __restrict__ vmean,
    float* __restrict__ kmean)
{
    const int bh = blockIdx.x;
    const int d = threadIdx.x & 63;
    const int which = threadIdx.x >> 6;
    const float* p = partial + ((size_t)which * B * H + bh) * CSEG * DK;
    float s = 0.f;
    #pragma unroll
    for (int g = 0; g < CSEG; ++g) s += p[g * DK + d];
    float* dst = which ? kmean : vmean;
    dst[bh * DK + d] = s / (float)N;
}

// ---------------------------------------------------------------------------
// Mdot[bh,row] = dot(q_row, kmean_bh)
// ---------------------------------------------------------------------------
__global__ __launch_bounds__(256) void qdot_kernel(
    const float* __restrict__ q, const float* __restrict__ kmean,
    float* __restrict__ Mdot)
{
    const int bh = blockIdx.y;
    const int row = blockIdx.x * 256 + threadIdx.x;
    __shared__ float km[DK];
    if (threadIdx.x < DK) km[threadIdx.x] = kmean[bh * DK + threadIdx.x];
    __syncthreads();
    const float* qr = &q[((size_t)bh * N + row) * DK];
    float s = 0.f;
    #pragma unroll
    for (int d4 = 0; d4 < DK; d4 += 4) {
        float4 v = *(const float4*)&qr[d4];
        s += v.x * km[d4] + v.y * km[d4 + 1] + v.z * km[d4 + 2] + v.w * km[d4 + 3];
    }
    Mdot[(size_t)bh * N + row] = s;
}

// ---------------------------------------------------------------------------
// MFMA row-max (3-term), gload staging. 2D grid (r9-verified, no swizzle).
// ---------------------------------------------------------------------------
__global__ __launch_bounds__(256) void row_stats_mfma(
    const u16* __restrict__ qh_, const u16* __restrict__ ql_,
    const u16* __restrict__ kh_, const u16* __restrict__ kl_,
    const float* __restrict__ Mdot, float* __restrict__ Mout,
    float* __restrict__ rowmax)
{
    __shared__ __align__(16) u16 Kh[64 * 64];
    __shared__ __align__(16) u16 Kl[64 * 64];
    const int tid = threadIdx.x, lane = tid & 63, wave = tid >> 6;
    const int bh = blockIdx.y;
    const int q0 = blockIdx.x * 128 + wave * 32;
    const int fr = lane & 15, g = lane >> 4;

    const u16* gsrc = (wave & 2) ? kl_ : kh_;
    u16* lbase = (wave & 2) ? Kl : Kh;
    const int cb = (wave & 1) * 256;

    short8v qfh[2][2], qfl[2][2];
    #pragma unroll
    for (int m = 0; m < 2; ++m)
        #pragma unroll
        for (int kk = 0; kk < 2; ++kk) {
            size_t qa = ((size_t)bh * N + q0 + m * 16 + fr) * DK + kk * 32 + g * 8;
            qfh[m][kk] = *(const short8v*)&qh_[qa];
            qfl[m][kk] = *(const short8v*)&ql_[qa];
        }

    f32x4 mx[2];
    mx[0] = (f32x4){-1e30f, -1e30f, -1e30f, -1e30f};
    mx[1] = mx[0];

    for (int kt = 0; kt < N; kt += 64) {
        __syncthreads();
        #pragma unroll
        for (int i = 0; i < 4; ++i) {
            int c = cb + i * 64 + lane;
            int row = c >> 3, sp = c & 7;
            int gs = sp ^ (row & 7);
            gload16(gsrc + ((size_t)bh * N + kt + row) * DK + gs * 8,
                    lbase + (size_t)(cb + i * 64) * 8);
        }
        __syncthreads();
        short8v bfh[4][2], bfl[4][2];
        #pragma unroll
        for (int n = 0; n < 4; ++n)
            #pragma unroll
            for (int kk = 0; kk < 2; ++kk) {
                int key = n * 16 + fr;
                int off = key * 64 + (((g + kk * 4) ^ (key & 7)) * 8);
                bfh[n][kk] = *(const short8v*)&Kh[off];
                bfl[n][kk] = *(const short8v*)&Kl[off];
            }
        #pragma unroll
        for (int m = 0; m < 2; ++m)
            #pragma unroll
            for (int n = 0; n < 4; ++n) {
                f32x4 a = {};
                #pragma unroll
                for (int kk = 0; kk < 2; ++kk) {
                    a = __builtin_amdgcn_mfma_f32_16x16x32_bf16(qfl[m][kk], bfh[n][kk], a, 0, 0, 0);
                    a = __builtin_amdgcn_mfma_f32_16x16x32_bf16(qfh[m][kk], bfl[n][kk], a, 0, 0, 0);
                    a = __builtin_amdgcn_mfma_f32_16x16x32_bf16(qfh[m][kk], bfh[n][kk], a, 0, 0, 0);
                }
                #pragma unroll
                for (int r = 0; r < 4; ++r) mx[m][r] = fmaxf(mx[m][r], a[r]);
            }
    }

    #pragma unroll
    for (int w = 1; w < 16; w <<= 1)
        #pragma unroll
        for (int m = 0; m < 2; ++m)
            #pragma unroll
            for (int r = 0; r < 4; ++r)
                mx[m][r] = fmaxf(mx[m][r], __shfl_xor(mx[m][r], w, 64));

    if (fr == 0) {
        #pragma unroll
        for (int m = 0; m < 2; ++m)
            #pragma unroll
            for (int r = 0; r < 4; ++r) {
                int row = q0 + m * 16 + g * 4 + r;
                size_t idx = (size_t)bh * N + row;
                float v = mx[m][r];
                rowmax[idx] = SCALE * v;
                Mout[idx]   = SCALE * (v - Mdot[idx]);
            }
    }
}

// ---------------------------------------------------------------------------
// Selection: thr (+cnt init) -> classify -> fp64 batched refine -> finalize.
// ---------------------------------------------------------------------------
__global__ __launch_bounds__(256) void topk_thr(
    const float* __restrict__ Mv, float* __restrict__ thr, int* __restrict__ cnt)
{
    const int bh = blockIdx.y;
    const int qi = blockIdx.x * 256 + threadIdx.x;
    if (blockIdx.x == 0 && threadIdx.x == 0) cnt[bh] = 0;
    __shared__ float Ms[N];
    for (int e = threadIdx.x; e < N; e += 256) Ms[e] = Mv[(size_t)bh * N + e];
    __syncthreads();
    const float mq = Ms[qi];
    int rank = 0;
    for (int j = 0; j < N; ++j) {
        float mj = Ms[j];
        rank += (mj > mq) || (mj == mq && j < qi);
    }
    if (rank == NTOP - 1) thr[bh] = mq;   // smallest kept (approx boundary)
}

__global__ __launch_bounds__(256) void band_classify(
    const float* __restrict__ Mv, const float* __restrict__ thr,
    int* __restrict__ cnt, int* __restrict__ band, int* __restrict__ keep)
{
    const int bh = blockIdx.y;
    const int row = blockIdx.x * 256 + threadIdx.x;
    const float m = Mv[(size_t)bh * N + row];
    const float t = thr[bh];
    int kp;
    if (fabsf(m - t) <= BAND_EPS) {
        int pos = atomicAdd(&cnt[bh], 1);
        if (pos < BAND_CAP) band[bh * BAND_CAP + pos] = row;
        kp = 0;
    } else {
        kp = (m > t) ? 1 : 0;
    }
    keep[(size_t)bh * N + row] = kp;
}

// Batched refine: one block per bh; each 64-key K tile staged ONCE serves
// up to 32 candidates (thread = cand*8 + keygroup, 8 keys/thread, fp64).
__global__ __launch_bounds__(256) void refine_kernel2(
    const float* __restrict__ q, const float* __restrict__ k,
    const int* __restrict__ cnt, const int* __restrict__ band,
    float* __restrict__ Mv)
{
    constexpr int LS = 69;
    __shared__ float Ks[64 * LS];
    __shared__ float qs[32][DK];
    const int bh = blockIdx.x;
    const int tid = threadIdx.x;
    const int nb = min(cnt[bh], BAND_CAP);
    const int cand = tid >> 3;      // 0..31
    const int kg = tid & 7;         // key group: keys kg*8 .. kg*8+7

    for (int c0 = 0; c0 < nb; c0 += 32) {
        const int nc = min(32, nb - c0);
        __syncthreads();            // prev chunk done with qs/Ks
        for (int e = tid; e < nc * DK; e += 256) {
            int ci = e >> 6, d = e & 63;
            qs[ci][d] = q[((size_t)bh * N + band[bh * BAND_CAP + c0 + ci]) * DK + d];
        }
        double mx = -1e30, sm = 0.0;
        for (int kt = 0; kt < N; kt += 64) {
            __syncthreads();
            #pragma unroll
            for (int p = 0; p < 4; ++p) {
                int idx = tid * 4 + p * 1024;
                int kr = idx >> 6, d = idx & 63;
                float4 x4 = *(const float4*)&k[((size_t)bh * N + kt + kr) * DK + d];
                Ks[kr * LS + d]     = x4.x;
                Ks[kr * LS + d + 1] = x4.y;
                Ks[kr * LS + d + 2] = x4.z;
                Ks[kr * LS + d + 3] = x4.w;
            }
            __syncthreads();
            if (cand < nc) {
                #pragma unroll
                for (int j = 0; j < 8; ++j) {
                    const int key = kg * 8 + j;
                    double s = 0.0;
                    #pragma unroll
                    for (int d = 0; d < DK; ++d)
                        s += (double)qs[cand][d] * (double)Ks[key * LS + d];
                    mx = fmax(mx, s);
                    sm += s;
                }
            }
        }
        #pragma unroll
        for (int w = 1; w < 8; w <<= 1) {
            mx = fmax(mx, __shfl_xor(mx, w, 64));
            sm += __shfl_xor(sm, w, 64);
        }
        if (kg == 0 && cand < nc) {
            const int row = band[bh * BAND_CAP + c0 + cand];
            Mv[(size_t)bh * N + row] =
                (float)((double)SCALE * (mx - sm / (double)N));
        }
    }
}

__global__ __launch_bounds__(256) void band_finalize(
    const float* __restrict__ Mv, const int* __restrict__ cnt,
    const int* __restrict__ band, int* __restrict__ keep,
    int* __restrict__ kidx)
{
    __shared__ unsigned char kL[N];
    __shared__ int   bRow[BAND_CAP];
    __shared__ float bM[BAND_CAP];
    __shared__ int aW[4];
    __shared__ int scan[256];

    const int bh = blockIdx.x;
    const int tid = threadIdx.x;
    const int lane = tid & 63, wid = tid >> 6;
    const int nb = min(cnt[bh], BAND_CAP);

    int above = 0;
    #pragma unroll
    for (int w = 0; w < 8; ++w) {
        int row = w * 256 + tid;
        int kp = keep[(size_t)bh * N + row];
        kL[row] = (unsigned char)kp;
        above += kp;
    }
    #pragma unroll
    for (int w = 1; w < 64; w <<= 1) above += __shfl_xor(above, w, 64);
    if (lane == 0) aW[wid] = above;
    for (int i = tid; i < nb; i += 256) {
        int r = band[bh * BAND_CAP + i];
        bRow[i] = r;
        bM[i] = Mv[(size_t)bh * N + r];
    }
    __syncthreads();
    const int nAbove = aW[0] + aW[1] + aW[2] + aW[3];

    for (int i = tid; i < nb; i += 256) {
        const float mi = bM[i];
        const int ri = bRow[i];
        int rank = nAbove;
        for (int j = 0; j < nb; ++j) {
            float mj = bM[j];
            rank += (mj > mi) || (mj == mi && bRow[j] < ri);
        }
        int kp = (rank < NTOP) ? 1 : 0;
        kL[ri] = (unsigned char)kp;
        keep[(size_t)bh * N + ri] = kp;
    }
    __syncthreads();

    int cntL = 0;
    #pragma unroll
    for (int r = 0; r < 8; ++r) cntL += kL[tid * 8 + r];
    scan[tid] = cntL;
    __syncthreads();
    for (int s = 1; s < 256; s <<= 1) {
        int v = (tid >= s) ? scan[tid - s] : 0;
        __syncthreads();
        scan[tid] += v;
        __syncthreads();
    }
    int pos = scan[tid] - cntL;
    #pragma unroll
    for (int r = 0; r < 8; ++r) {
        int row = tid * 8 + r;
        if (kL[row]) kidx[bh * NTOP + pos++] = row;
    }
}

// ---------------------------------------------------------------------------
// Fill non-kept rows of attn_out with vmean. grid (N/64, B*H)
// ---------------------------------------------------------------------------
__global__ __launch_bounds__(256) void fill_nonkept(
    const int* __restrict__ keep, const float* __restrict__ vmean,
    float* __restrict__ attn_out)
{
    const int bh = blockIdx.y;
    const int b = bh >> 4, h = bh & 15;
    const int d = threadIdx.x & 63;
    const int rr = threadIdx.x >> 6;
    const float vm = vmean[bh * DK + d];
    #pragma unroll
    for (int i = 0; i < 16; ++i) {
        int row = blockIdx.x * 64 + i * 4 + rr;
        if (!keep[(size_t)bh * N + row])
            attn_out[((size_t)b * N + row) * C + h * DK + d] = vm;
    }
}

// ---------------------------------------------------------------------------
// MFMA attention on kept rows; gload staging + setprio (r10-verified).
// ---------------------------------------------------------------------------
__global__ __launch_bounds__(256) void attn_mfma(
    const u16* __restrict__ qh_, const u16* __restrict__ ql_,
    const u16* __restrict__ kh_, const u16* __restrict__ kl_,
    const u16* __restrict__ vth_, const u16* __restrict__ vtl_,
    const float* __restrict__ rowmax, const int* __restrict__ kidx,
    float* __restrict__ attn_out)
{
    __shared__ __align__(16) u16 Kh[64 * 64], Kl[64 * 64];
    __shared__ __align__(16) u16 Vh[64 * 64], Vl[64 * 64];
    __shared__ __align__(16) u16 Ph[4][16 * 64], Pl[4][16 * 64];

    const int tid = threadIdx.x, lane = tid & 63, wave = tid >> 6;
    const int wg = blockIdx.x;
    const int bh = ((wg >> 6) << 3) | (wg & 7);
    const int xblk = (wg >> 3) & 7;
    const int b = bh >> 4, h = bh & 15;
    const int q0 = xblk * 64 + wave * 16;
    const int fr = lane & 15, sl = lane >> 4;

    const bool isV = (wave >= 2);
    const u16* ksrc = (wave & 1) ? kl_ : kh_;
    const u16* vsrc = (wave & 1) ? vtl_ : vth_;
    u16* lbase = (wave == 0) ? Kh : (wave == 1) ? Kl : (wave == 2) ? Vh : Vl;
    const size_t kbase0 = (size_t)bh * N * DK;
    const size_t vbase0 = (size_t)bh * DK * N;

    const int* kix = kidx + bh * NTOP;
    const int qrow_f = kix[q0 + fr];
    int qr_o[4]; float rmax_r[4];
    #pragma unroll
    for (int r = 0; r < 4; ++r) {
        qr_o[r] = kix[q0 + sl * 4 + r];
        rmax_r[r] = rowmax[(size_t)bh * N + qr_o[r]];
    }

    short8v qfh[2], qfl[2];
    #pragma unroll
    for (int kk = 0; kk < 2; ++kk) {
        size_t qa = ((size_t)bh * N + qrow_f) * DK + kk * 32 + sl * 8;
        qfh[kk] = *(const short8v*)&qh_[qa];
        qfl[kk] = *(const short8v*)&ql_[qa];
    }

    f32x4 opv[4] = {};
    float lsum[4] = {};

    for (int kt = 0; kt < N; kt += 64) {
        __syncthreads();
        #pragma unroll
        for (int i = 0; i < 8; ++i) {
            int c = i * 64 + lane;
            int row = c >> 3, sp = c & 7;
            int gs = sp ^ (row & 7);
            const u16* g = isV ? (vsrc + vbase0 + (size_t)row * N + kt + gs * 8)
                               : (ksrc + kbase0 + (size_t)(kt + row) * DK + gs * 8);
            gload16(g, lbase + (size_t)i * 512);
        }
        __syncthreads();

        #pragma unroll
        for (int n = 0; n < 4; ++n) {
            f32x4 a = {};
            __builtin_amdgcn_s_setprio(1);
            #pragma unroll
            for (int kk = 0; kk < 2; ++kk) {
                int key = n * 16 + fr;
                int off = key * 64 + (((sl + kk * 4) ^ (key & 7)) * 8);
                short8v bh_f = *(const short8v*)&Kh[off];
                short8v bl_f = *(const short8v*)&Kl[off];
                a = __builtin_amdgcn_mfma_f32_16x16x32_bf16(qfl[kk], bh_f, a, 0, 0, 0);
                a = __builtin_amdgcn_mfma_f32_16x16x32_bf16(qfh[kk], bl_f, a, 0, 0, 0);
                a = __builtin_amdgcn_mfma_f32_16x16x32_bf16(qfh[kk], bh_f, a, 0, 0, 0);
            }
            __builtin_amdgcn_s_setprio(0);
            #pragma unroll
            for (int r = 0; r < 4; ++r) {
                float p = __expf(a[r] * SCALE - rmax_r[r]);
                lsum[r] += p;
                u16 ph = bf16_rne(p);
                u16 pl = bf16_rne(p - __uint_as_float((unsigned)ph << 16));
                int q_l = sl * 4 + r;
                int key = n * 16 + fr;
                int off = q_l * 64 + (((key >> 3) ^ (q_l & 7)) * 8) + (key & 7);
                Ph[wave][off] = ph;
                Pl[wave][off] = pl;
            }
        }

        __builtin_amdgcn_s_setprio(1);
        #pragma unroll
        for (int kk = 0; kk < 2; ++kk) {
            int aoff = fr * 64 + (((kk * 4 + sl) ^ (fr & 7)) * 8);
            short8v pah = *(const short8v*)&Ph[wave][aoff];
            short8v pal = *(const short8v*)&Pl[wave][aoff];
            #pragma unroll
            for (int n = 0; n < 4; ++n) {
                int d = n * 16 + fr;
                int voff = d * 64 + (((kk * 4 + sl) ^ (d & 7)) * 8);
                short8v vhf = *(const short8v*)&Vh[voff];
                short8v vlf = *(const short8v*)&Vl[voff];
                opv[n] = __builtin_amdgcn_mfma_f32_16x16x32_bf16(pal, vhf, opv[n], 0, 0, 0);
                opv[n] = __builtin_amdgcn_mfma_f32_16x16x32_bf16(pah, vlf, opv[n], 0, 0, 0);
                opv[n] = __builtin_amdgcn_mfma_f32_16x16x32_bf16(pah, vhf, opv[n], 0, 0, 0);
            }
        }
        __builtin_amdgcn_s_setprio(0);
    }

    #pragma unroll
    for (int w = 1; w < 16; w <<= 1)
        #pragma unroll
        for (int r = 0; r < 4; ++r)
            lsum[r] += __shfl_xor(lsum[r], w, 64);

    #pragma unroll
    for (int r = 0; r < 4; ++r) {
        const float inv = 1.0f / lsum[r];
        float* orow = attn_out + ((size_t)b * N + qr_o[r]) * C + h * DK;
        #pragma unroll
        for (int n = 0; n < 4; ++n)
            orow[n * 16 + fr] = opv[n][r] * inv;
    }
}

// ---------------------------------------------------------------------------
extern "C" void kernel_launch(void* const* d_in, const int* in_sizes, int n_in,
                              void* d_out, int out_size, void* d_ws, size_t ws_size,
                              hipStream_t stream)
{
    const float* x    = (const float*)d_in[0];
    const float* Wqkv = (const float*)d_in[1];
    const float* bqkv = (const float*)d_in[2];
    const float* Wout = (const float*)d_in[3];
    const float* bout = (const float*)d_in[4];
    float* out = (float*)d_out;

    char* ws = (char*)d_ws;
    size_t off = 0;
    auto alloc = [&](size_t bytes) -> void* {
        void* p = ws + off;
        off += (bytes + 255) & ~(size_t)255;
        return p;
    };

    const size_t BHND = (size_t)B * H * N * DK;       // 4 Mi elems
    float* q        = (float*)alloc(BHND * 4);
    float* kbuf     = (float*)alloc(BHND * 4);
    float* vbuf     = (float*)alloc(BHND * 4);
    float* attn_out = (float*)alloc((size_t)B * N * C * 4);
    u16* cvAhi = (u16*)alloc((size_t)B * N * C * 2);  // x / attn_out hi
    u16* cvAlo = (u16*)alloc((size_t)B * N * C * 2);
    u16* cvBhi = (u16*)alloc((size_t)3 * C * C * 2);
    u16* cvBlo = (u16*)alloc((size_t)3 * C * C * 2);
    u16* qhi   = (u16*)alloc(BHND * 2);
    u16* qlo   = (u16*)alloc(BHND * 2);
    u16* khi   = (u16*)alloc(BHND * 2);
    u16* klo   = (u16*)alloc(BHND * 2);
    u16* vthi  = (u16*)alloc(BHND * 2);
    u16* vtlo  = (u16*)alloc(BHND * 2);
    float* Mbuf     = (float*)alloc((size_t)B * H * N * 4);
    float* rmaxbuf  = (float*)alloc((size_t)B * H * N * 4);
    float* Mdot     = (float*)alloc((size_t)B * H * N * 4);
    int*   keep     = (int*)  alloc((size_t)B * H * N * 4);
    int*   kidx     = (int*)  alloc((size_t)B * H * NTOP * 4);
    float* vmeanbuf = (float*)alloc((size_t)B * H * DK * 4);
    float* kmeanbuf = (float*)alloc((size_t)B * H * DK * 4);
    float* partbuf  = (float*)alloc((size_t)2 * B * H * CSEG * DK * 4);
    float* thrbuf   = (float*)alloc((size_t)B * H * 4);
    int*   cntbuf   = (int*)  alloc((size_t)B * H * 4);
    int*   bandbuf  = (int*)  alloc((size_t)B * H * BAND_CAP * 4);

    const int nX = B * N * C;        // 4M
    const int nW = 3 * C * C;        // 3M
    const int nWo = C * C;           // 1M

    // 1. convert x, Wqkv to bf16 hi/lo
    convert_hilo<<<nX / 1024, 256, 0, stream>>>(x, cvAhi, cvAlo, nX);
    convert_hilo<<<nW / 1024, 256, 0, stream>>>(Wqkv, cvBhi, cvBlo, nW);

    // 2. QKV projection (2D grid — r9-verified config)
    gemm_mfma<0><<<dim3(3 * C / 128, (B * N) / 128), 256, 0, stream>>>(
        cvAhi, cvAlo, cvBhi, cvBlo, bqkv, nullptr, q, kbuf, vbuf, C);

    // 3. convert q,k hi/lo (one launch); v transposed hi/lo
    convert_hilo2<<<dim3(nX / 1024, 2), 256, 0, stream>>>(
        q, kbuf, qhi, qlo, khi, klo, nX);
    convert_hilo_T<<<dim3(N / 64, B * H), 256, 0, stream>>>(vbuf, vthi, vtlo);

    // 4. column means of v and k (fused)
    colsum_part2<<<dim3(CSEG, B * H, 2), 256, 0, stream>>>(vbuf, kbuf, partbuf);
    colsum_final2<<<B * H, 128, 0, stream>>>(partbuf, vmeanbuf, kmeanbuf);

    // 5. mean term per row: Mdot = q . kmean
    qdot_kernel<<<dim3(N / 256, B * H), 256, 0, stream>>>(q, kmeanbuf, Mdot);

    // 6. MFMA approximate row max -> M, rowmax (2D grid)
    row_stats_mfma<<<dim3(N / 128, B * H), 256, 0, stream>>>(
        qhi, qlo, khi, klo, Mdot, Mbuf, rmaxbuf);

    // 7. selection: thr (+cnt init) -> classify -> batched fp64 refine -> finalize
    topk_thr<<<dim3(N / 256, B * H), 256, 0, stream>>>(Mbuf, thrbuf, cntbuf);
    band_classify<<<dim3(N / 256, B * H), 256, 0, stream>>>(Mbuf, thrbuf, cntbuf, bandbuf, keep);
    refine_kernel2<<<B * H, 256, 0, stream>>>(q, kbuf, cntbuf, bandbuf, Mbuf);
    band_finalize<<<B * H, 256, 0, stream>>>(Mbuf, cntbuf, bandbuf, keep, kidx);

    // 8. fill non-kept rows; MFMA attention on kept rows
    fill_nonkept<<<dim3(N / 64, B * H), 256, 0, stream>>>(keep, vmeanbuf, attn_out);
    attn_mfma<<<256, 256, 0, stream>>>(
        qhi, qlo, khi, klo, vthi, vtlo, rmaxbuf, kidx, attn_out);

    // 9. Output projection (2D grid)
    convert_hilo<<<nX / 1024, 256, 0, stream>>>(attn_out, cvAhi, cvAlo, nX);
    convert_hilo<<<nWo / 1024, 256, 0, stream>>>(Wout, cvBhi, cvBlo, nWo);
    gemm_mfma<1><<<dim3(C / 128, (B * N) / 128), 256, 0, stream>>>(
        cvAhi, cvAlo, cvBhi, cvBlo, bout, out, nullptr, nullptr, nullptr, C);
}

// Round 12
// 401.385 us; speedup vs baseline: 1.2098x; 1.2098x over previous
//
#include <hip/hip_runtime.h>
#include <math.h>

typedef unsigned short u16;
typedef __attribute__((ext_vector_type(8))) short short8v;  // 8 bf16 operand frag
typedef __attribute__((ext_vector_type(4))) float f32x4;    // MFMA accumulator

constexpr int B  = 2;
constexpr int N  = 2048;
constexpr int C  = 1024;
constexpr int H  = 16;
constexpr int DK = 64;
constexpr int NTOP = 512;
constexpr float SCALE = 0.125f;  // 1/sqrt(64)
constexpr int   BAND_CAP = 1024;
constexpr float BAND_EPS = 2e-3f;   // covers 3-term split-bf16 M error (~1e-4)
constexpr int   CSEG = 16;          // column-sum segments per bh

// ---------------------------------------------------------------------------
// async global -> LDS, 16B per lane. (verified r8)
// ---------------------------------------------------------------------------
__device__ __forceinline__ void gload16(const u16* g, u16* l) {
    __builtin_amdgcn_global_load_lds(
        (const __attribute__((address_space(1))) unsigned int*)g,
        (__attribute__((address_space(3))) unsigned int*)l,
        16, 0, 0);
}

// ---------------------------------------------------------------------------
// fp32 -> bf16 hi/lo split (RNE)
// ---------------------------------------------------------------------------
__device__ __forceinline__ u16 bf16_rne(float x) {
    unsigned u = __float_as_uint(x);
    unsigned r = u + 0x7fffu + ((u >> 16) & 1u);
    return (u16)(r >> 16);
}

__global__ __launch_bounds__(256) void convert_hilo(
    const float* __restrict__ src, u16* __restrict__ hi, u16* __restrict__ lo, int n)
{
    int i = (blockIdx.x * 256 + threadIdx.x) * 4;
    if (i >= n) return;
    float4 v = *(const float4*)&src[i];
    u16 h0 = bf16_rne(v.x), h1 = bf16_rne(v.y), h2 = bf16_rne(v.z), h3 = bf16_rne(v.w);
    float f0 = __uint_as_float((unsigned)h0 << 16);
    float f1 = __uint_as_float((unsigned)h1 << 16);
    float f2 = __uint_as_float((unsigned)h2 << 16);
    float f3 = __uint_as_float((unsigned)h3 << 16);
    *(ushort4*)&hi[i] = make_ushort4(h0, h1, h2, h3);
    *(ushort4*)&lo[i] = make_ushort4(bf16_rne(v.x - f0), bf16_rne(v.y - f1),
                                     bf16_rne(v.z - f2), bf16_rne(v.w - f3));
}

// two-source variant (q and k in one launch); grid (n/1024, 2)
__global__ __launch_bounds__(256) void convert_hilo2(
    const float* __restrict__ a, const float* __restrict__ b,
    u16* __restrict__ ah, u16* __restrict__ al,
    u16* __restrict__ bh_, u16* __restrict__ bl_, int n)
{
    const float* src = blockIdx.y ? b : a;
    u16* hi = blockIdx.y ? bh_ : ah;
    u16* lo = blockIdx.y ? bl_ : al;
    int i = (blockIdx.x * 256 + threadIdx.x) * 4;
    if (i >= n) return;
    float4 v = *(const float4*)&src[i];
    u16 h0 = bf16_rne(v.x), h1 = bf16_rne(v.y), h2 = bf16_rne(v.z), h3 = bf16_rne(v.w);
    float f0 = __uint_as_float((unsigned)h0 << 16);
    float f1 = __uint_as_float((unsigned)h1 << 16);
    float f2 = __uint_as_float((unsigned)h2 << 16);
    float f3 = __uint_as_float((unsigned)h3 << 16);
    *(ushort4*)&hi[i] = make_ushort4(h0, h1, h2, h3);
    *(ushort4*)&lo[i] = make_ushort4(bf16_rne(v.x - f0), bf16_rne(v.y - f1),
                                     bf16_rne(v.z - f2), bf16_rne(v.w - f3));
}

// ---------------------------------------------------------------------------
// Transposed convert: v (bh, key, d) fp32 -> vt hi/lo (bh, d, key) bf16. (r6)
// ---------------------------------------------------------------------------
__global__ __launch_bounds__(256) void convert_hilo_T(
    const float* __restrict__ v, u16* __restrict__ th, u16* __restrict__ tl)
{
    constexpr int LS = 68;
    __shared__ u16 Sh[64 * LS], Sl[64 * LS];
    const int bh = blockIdx.y;
    const int kt = blockIdx.x * 64;
    const int tid = threadIdx.x;
    #pragma unroll
    for (int p = 0; p < 4; ++p) {
        int idx = tid * 4 + p * 1024;
        int key = idx >> 6, d = idx & 63;
        float4 x4 = *(const float4*)&v[((size_t)bh * N + kt + key) * DK + d];
        float xs[4] = {x4.x, x4.y, x4.z, x4.w};
        ushort4 hh, ll;
        u16* hp = (u16*)&hh; u16* lp = (u16*)&ll;
        #pragma unroll
        for (int j = 0; j < 4; ++j) {
            u16 h = bf16_rne(xs[j]);
            hp[j] = h;
            lp[j] = bf16_rne(xs[j] - __uint_as_float((unsigned)h << 16));
        }
        *(ushort4*)&Sh[key * LS + d] = hh;
        *(ushort4*)&Sl[key * LS + d] = ll;
    }
    __syncthreads();
    const int d = tid >> 2, seg = tid & 3;
    u16 bufh[16], bufl[16];
    #pragma unroll
    for (int i = 0; i < 16; ++i) {
        bufh[i] = Sh[(seg * 16 + i) * LS + d];
        bufl[i] = Sl[(seg * 16 + i) * LS + d];
    }
    size_t oa = ((size_t)bh * DK + d) * N + kt + seg * 16;
    *(uint4*)&th[oa] = ((uint4*)bufh)[0];
    *(uint4*)&th[oa + 8] = ((uint4*)bufh)[1];
    *(uint4*)&tl[oa] = ((uint4*)bufl)[0];
    *(uint4*)&tl[oa + 8] = ((uint4*)bufl)[1];
}

// ---------------------------------------------------------------------------
// Split-bf16 MFMA GEMM: 128x128 tile, BK=32, 4 waves, gload staging.
// 2D grid (r9-verified config — no swizzle).
// ---------------------------------------------------------------------------
template <int MODE>
__global__ __launch_bounds__(256) void gemm_mfma(
    const u16* __restrict__ Ahi, const u16* __restrict__ Alo,
    const u16* __restrict__ Bhi, const u16* __restrict__ Blo,
    const float* __restrict__ bias, float* __restrict__ out,
    float* __restrict__ qb, float* __restrict__ kb, float* __restrict__ vb,
    int K)
{
    __shared__ __align__(16) u16 Ah[128 * 32], Al[128 * 32];
    __shared__ __align__(16) u16 Bh[128 * 32], Bl[128 * 32];

    const int tid = threadIdx.x;
    const int m0 = blockIdx.y * 128;
    const int n0 = blockIdx.x * 128;
    const int lane = tid & 63;
    const int wave = tid >> 6;
    const int wr = wave >> 1, wc = wave & 1;
    const int fr = lane & 15, sl = lane >> 4;

    const u16* gsrc = (wave == 0) ? Ahi + (size_t)m0 * K
                    : (wave == 1) ? Alo + (size_t)m0 * K
                    : (wave == 2) ? Bhi + (size_t)n0 * K
                                  : Blo + (size_t)n0 * K;
    u16* lbase = (wave == 0) ? Ah : (wave == 1) ? Al : (wave == 2) ? Bh : Bl;

    f32x4 acc[4][4] = {};

    for (int k0 = 0; k0 < K; k0 += 32) {
        __syncthreads();
        #pragma unroll
        for (int i = 0; i < 8; ++i) {
            int c = i * 64 + lane;               // chunk = 16B = 8 u16
            int row = c >> 2, sp = c & 3;
            int gs = sp ^ ((row >> 1) & 3);
            gload16(gsrc + (size_t)row * K + k0 + gs * 8, lbase + i * 512);
        }
        __syncthreads();

        short8v afh[4], afl[4], bfh[4], bfl[4];
        #pragma unroll
        for (int m = 0; m < 4; ++m) {
            int row = wr * 64 + m * 16 + fr;
            int off = row * 32 + ((sl ^ ((row >> 1) & 3)) * 8);
            afh[m] = *(const short8v*)&Ah[off];
            afl[m] = *(const short8v*)&Al[off];
        }
        #pragma unroll
        for (int n = 0; n < 4; ++n) {
            int row = wc * 64 + n * 16 + fr;
            int off = row * 32 + ((sl ^ ((row >> 1) & 3)) * 8);
            bfh[n] = *(const short8v*)&Bh[off];
            bfl[n] = *(const short8v*)&Bl[off];
        }
        #pragma unroll
        for (int m = 0; m < 4; ++m)
            #pragma unroll
            for (int n = 0; n < 4; ++n) {
                acc[m][n] = __builtin_amdgcn_mfma_f32_16x16x32_bf16(afh[m], bfh[n], acc[m][n], 0, 0, 0);
                acc[m][n] = __builtin_amdgcn_mfma_f32_16x16x32_bf16(afh[m], bfl[n], acc[m][n], 0, 0, 0);
                acc[m][n] = __builtin_amdgcn_mfma_f32_16x16x32_bf16(afl[m], bfh[n], acc[m][n], 0, 0, 0);
            }
    }

    #pragma unroll
    for (int m = 0; m < 4; ++m)
        #pragma unroll
        for (int n = 0; n < 4; ++n)
            #pragma unroll
            for (int r = 0; r < 4; ++r) {
                int grow = m0 + wr * 64 + m * 16 + sl * 4 + r;
                int gcol = n0 + wc * 64 + n * 16 + fr;
                float val = acc[m][n][r] + bias[gcol];
                if (MODE == 0) {
                    int t = gcol >> 10, h = (gcol >> 6) & 15, d = gcol & 63;
                    int bb = grow >> 11, nn = grow & (N - 1);
                    float* dst = (t == 0) ? qb : (t == 1) ? kb : vb;
                    dst[(((size_t)bb * H + h) * N + nn) * DK + d] = val;
                } else {
                    out[(size_t)grow * C + gcol] = val;
                }
            }
}

// ---------------------------------------------------------------------------
// Column sums over v and k in one launch.  grid (CSEG, B*H, 2), z: 0=v 1=k.
// ---------------------------------------------------------------------------
__global__ __launch_bounds__(256) void colsum_part2(
    const float* __restrict__ v, const float* __restrict__ k,
    float* __restrict__ partial)
{
    const int bh = blockIdx.y, seg = blockIdx.x, which = blockIdx.z;
    const float* src = which ? k : v;
    const int d = threadIdx.x & 63;
    const int sub = threadIdx.x >> 6;
    const int k0 = seg * (N / CSEG);
    float s = 0.f;
    for (int kk = sub; kk < N / CSEG; kk += 4)
        s += src[((size_t)bh * N + k0 + kk) * DK + d];
    __shared__ float part[4][64];
    part[sub][d] = s;
    __syncthreads();
    if (threadIdx.x < 64)
        partial[(((size_t)which * B * H + bh) * CSEG + seg) * DK + d] =
            part[0][d] + part[1][d] + part[2][d] + part[3][d];
}

// grid (B*H), 128 threads: tid<64 -> vmean, tid>=64 -> kmean
__global__ __launch_bounds__(128) void colsum_final2(
    const float* __restrict__ partial, float* __restrict__ vmean,
    float* __restrict__ kmean)
{
    const int bh = blockIdx.x;
    const int d = threadIdx.x & 63;
    const int which = threadIdx.x >> 6;
    const float* p = partial + ((size_t)which * B * H + bh) * CSEG * DK;
    float s = 0.f;
    #pragma unroll
    for (int g = 0; g < CSEG; ++g) s += p[g * DK + d];
    float* dst = which ? kmean : vmean;
    dst[bh * DK + d] = s / (float)N;
}

// ---------------------------------------------------------------------------
// Mdot[bh,row] = dot(q_row, kmean_bh)
// ---------------------------------------------------------------------------
__global__ __launch_bounds__(256) void qdot_kernel(
    const float* __restrict__ q, const float* __restrict__ kmean,
    float* __restrict__ Mdot)
{
    const int bh = blockIdx.y;
    const int row = blockIdx.x * 256 + threadIdx.x;
    __shared__ float km[DK];
    if (threadIdx.x < DK) km[threadIdx.x] = kmean[bh * DK + threadIdx.x];
    __syncthreads();
    const float* qr = &q[((size_t)bh * N + row) * DK];
    float s = 0.f;
    #pragma unroll
    for (int d4 = 0; d4 < DK; d4 += 4) {
        float4 v = *(const float4*)&qr[d4];
        s += v.x * km[d4] + v.y * km[d4 + 1] + v.z * km[d4 + 2] + v.w * km[d4 + 3];
    }
    Mdot[(size_t)bh * N + row] = s;
}

// ---------------------------------------------------------------------------
// MFMA row-max (3-term), gload staging. 2D grid (r9-verified, no swizzle).
// ---------------------------------------------------------------------------
__global__ __launch_bounds__(256) void row_stats_mfma(
    const u16* __restrict__ qh_, const u16* __restrict__ ql_,
    const u16* __restrict__ kh_, const u16* __restrict__ kl_,
    const float* __restrict__ Mdot, float* __restrict__ Mout,
    float* __restrict__ rowmax)
{
    __shared__ __align__(16) u16 Kh[64 * 64];
    __shared__ __align__(16) u16 Kl[64 * 64];
    const int tid = threadIdx.x, lane = tid & 63, wave = tid >> 6;
    const int bh = blockIdx.y;
    const int q0 = blockIdx.x * 128 + wave * 32;
    const int fr = lane & 15, g = lane >> 4;

    const u16* gsrc = (wave & 2) ? kl_ : kh_;
    u16* lbase = (wave & 2) ? Kl : Kh;
    const int cb = (wave & 1) * 256;

    short8v qfh[2][2], qfl[2][2];
    #pragma unroll
    for (int m = 0; m < 2; ++m)
        #pragma unroll
        for (int kk = 0; kk < 2; ++kk) {
            size_t qa = ((size_t)bh * N + q0 + m * 16 + fr) * DK + kk * 32 + g * 8;
            qfh[m][kk] = *(const short8v*)&qh_[qa];
            qfl[m][kk] = *(const short8v*)&ql_[qa];
        }

    f32x4 mx[2];
    mx[0] = (f32x4){-1e30f, -1e30f, -1e30f, -1e30f};
    mx[1] = mx[0];

    for (int kt = 0; kt < N; kt += 64) {
        __syncthreads();
        #pragma unroll
        for (int i = 0; i < 4; ++i) {
            int c = cb + i * 64 + lane;
            int row = c >> 3, sp = c & 7;
            int gs = sp ^ (row & 7);
            gload16(gsrc + ((size_t)bh * N + kt + row) * DK + gs * 8,
                    lbase + (size_t)(cb + i * 64) * 8);
        }
        __syncthreads();
        short8v bfh[4][2], bfl[4][2];
        #pragma unroll
        for (int n = 0; n < 4; ++n)
            #pragma unroll
            for (int kk = 0; kk < 2; ++kk) {
                int key = n * 16 + fr;
                int off = key * 64 + (((g + kk * 4) ^ (key & 7)) * 8);
                bfh[n][kk] = *(const short8v*)&Kh[off];
                bfl[n][kk] = *(const short8v*)&Kl[off];
            }
        #pragma unroll
        for (int m = 0; m < 2; ++m)
            #pragma unroll
            for (int n = 0; n < 4; ++n) {
                f32x4 a = {};
                #pragma unroll
                for (int kk = 0; kk < 2; ++kk) {
                    a = __builtin_amdgcn_mfma_f32_16x16x32_bf16(qfl[m][kk], bfh[n][kk], a, 0, 0, 0);
                    a = __builtin_amdgcn_mfma_f32_16x16x32_bf16(qfh[m][kk], bfl[n][kk], a, 0, 0, 0);
                    a = __builtin_amdgcn_mfma_f32_16x16x32_bf16(qfh[m][kk], bfh[n][kk], a, 0, 0, 0);
                }
                #pragma unroll
                for (int r = 0; r < 4; ++r) mx[m][r] = fmaxf(mx[m][r], a[r]);
            }
    }

    #pragma unroll
    for (int w = 1; w < 16; w <<= 1)
        #pragma unroll
        for (int m = 0; m < 2; ++m)
            #pragma unroll
            for (int r = 0; r < 4; ++r)
                mx[m][r] = fmaxf(mx[m][r], __shfl_xor(mx[m][r], w, 64));

    if (fr == 0) {
        #pragma unroll
        for (int m = 0; m < 2; ++m)
            #pragma unroll
            for (int r = 0; r < 4; ++r) {
                int row = q0 + m * 16 + g * 4 + r;
                size_t idx = (size_t)bh * N + row;
                float v = mx[m][r];
                rowmax[idx] = SCALE * v;
                Mout[idx]   = SCALE * (v - Mdot[idx]);
            }
    }
}

// ---------------------------------------------------------------------------
// Selection: thr (+cnt init) -> classify -> fp64 refine (r10-verified) ->
// finalize.
// ---------------------------------------------------------------------------
__global__ __launch_bounds__(256) void topk_thr(
    const float* __restrict__ Mv, float* __restrict__ thr, int* __restrict__ cnt)
{
    const int bh = blockIdx.y;
    const int qi = blockIdx.x * 256 + threadIdx.x;
    if (blockIdx.x == 0 && threadIdx.x == 0) cnt[bh] = 0;
    __shared__ float Ms[N];
    for (int e = threadIdx.x; e < N; e += 256) Ms[e] = Mv[(size_t)bh * N + e];
    __syncthreads();
    const float mq = Ms[qi];
    int rank = 0;
    for (int j = 0; j < N; ++j) {
        float mj = Ms[j];
        rank += (mj > mq) || (mj == mq && j < qi);
    }
    if (rank == NTOP - 1) thr[bh] = mq;   // smallest kept (approx boundary)
}

__global__ __launch_bounds__(256) void band_classify(
    const float* __restrict__ Mv, const float* __restrict__ thr,
    int* __restrict__ cnt, int* __restrict__ band, int* __restrict__ keep)
{
    const int bh = blockIdx.y;
    const int row = blockIdx.x * 256 + threadIdx.x;
    const float m = Mv[(size_t)bh * N + row];
    const float t = thr[bh];
    int kp;
    if (fabsf(m - t) <= BAND_EPS) {
        int pos = atomicAdd(&cnt[bh], 1);
        if (pos < BAND_CAP) band[bh * BAND_CAP + pos] = row;
        kp = 0;
    } else {
        kp = (m > t) ? 1 : 0;
    }
    keep[(size_t)bh * N + row] = kp;
}

// Block-per-candidate (strided): LDS-staged coalesced K, fp64 exact dot.
// grid (32, B*H), 256 threads.  (r10-verified — restored after r11 regression)
__global__ __launch_bounds__(256) void refine_kernel(
    const float* __restrict__ q, const float* __restrict__ k,
    const int* __restrict__ cnt, const int* __restrict__ band,
    float* __restrict__ Mv)
{
    constexpr int LS = 69;
    __shared__ float Ks[64 * LS];
    __shared__ float qs[DK];
    const int bh = blockIdx.y;
    const int tid = threadIdx.x;
    const int n = min(cnt[bh], BAND_CAP);
    for (int ci = blockIdx.x; ci < n; ci += 32) {
        const int row = band[bh * BAND_CAP + ci];
        __syncthreads();
        if (tid < DK) qs[tid] = q[((size_t)bh * N + row) * DK + tid];
        double mx = -1e30, sm = 0.0;
        for (int kt = 0; kt < N; kt += 64) {
            __syncthreads();
            #pragma unroll
            for (int p = 0; p < 4; ++p) {
                int idx = tid * 4 + p * 1024;
                int kr = idx >> 6, d = idx & 63;
                float4 x4 = *(const float4*)&k[((size_t)bh * N + kt + kr) * DK + d];
                Ks[kr * LS + d]     = x4.x;
                Ks[kr * LS + d + 1] = x4.y;
                Ks[kr * LS + d + 2] = x4.z;
                Ks[kr * LS + d + 3] = x4.w;
            }
            __syncthreads();
            if (tid < 64) {
                double s = 0.0;
                #pragma unroll
                for (int d = 0; d < DK; ++d)
                    s += (double)qs[d] * (double)Ks[tid * LS + d];
                mx = fmax(mx, s);
                sm += s;
            }
        }
        if (tid < 64) {
            #pragma unroll
            for (int w = 1; w < 64; w <<= 1) {
                mx = fmax(mx, __shfl_xor(mx, w, 64));
                sm += __shfl_xor(sm, w, 64);
            }
            if (tid == 0)
                Mv[(size_t)bh * N + row] = (float)((double)SCALE * (mx - sm / (double)N));
        }
    }
}

__global__ __launch_bounds__(256) void band_finalize(
    const float* __restrict__ Mv, const int* __restrict__ cnt,
    const int* __restrict__ band, int* __restrict__ keep,
    int* __restrict__ kidx)
{
    __shared__ unsigned char kL[N];
    __shared__ int   bRow[BAND_CAP];
    __shared__ float bM[BAND_CAP];
    __shared__ int aW[4];
    __shared__ int scan[256];

    const int bh = blockIdx.x;
    const int tid = threadIdx.x;
    const int lane = tid & 63, wid = tid >> 6;
    const int nb = min(cnt[bh], BAND_CAP);

    int above = 0;
    #pragma unroll
    for (int w = 0; w < 8; ++w) {
        int row = w * 256 + tid;
        int kp = keep[(size_t)bh * N + row];
        kL[row] = (unsigned char)kp;
        above += kp;
    }
    #pragma unroll
    for (int w = 1; w < 64; w <<= 1) above += __shfl_xor(above, w, 64);
    if (lane == 0) aW[wid] = above;
    for (int i = tid; i < nb; i += 256) {
        int r = band[bh * BAND_CAP + i];
        bRow[i] = r;
        bM[i] = Mv[(size_t)bh * N + r];
    }
    __syncthreads();
    const int nAbove = aW[0] + aW[1] + aW[2] + aW[3];

    for (int i = tid; i < nb; i += 256) {
        const float mi = bM[i];
        const int ri = bRow[i];
        int rank = nAbove;
        for (int j = 0; j < nb; ++j) {
            float mj = bM[j];
            rank += (mj > mi) || (mj == mi && bRow[j] < ri);
        }
        int kp = (rank < NTOP) ? 1 : 0;
        kL[ri] = (unsigned char)kp;
        keep[(size_t)bh * N + ri] = kp;
    }
    __syncthreads();

    int cntL = 0;
    #pragma unroll
    for (int r = 0; r < 8; ++r) cntL += kL[tid * 8 + r];
    scan[tid] = cntL;
    __syncthreads();
    for (int s = 1; s < 256; s <<= 1) {
        int v = (tid >= s) ? scan[tid - s] : 0;
        __syncthreads();
        scan[tid] += v;
        __syncthreads();
    }
    int pos = scan[tid] - cntL;
    #pragma unroll
    for (int r = 0; r < 8; ++r) {
        int row = tid * 8 + r;
        if (kL[row]) kidx[bh * NTOP + pos++] = row;
    }
}

// ---------------------------------------------------------------------------
// Fill non-kept rows of attn_out with vmean. grid (N/64, B*H)
// ---------------------------------------------------------------------------
__global__ __launch_bounds__(256) void fill_nonkept(
    const int* __restrict__ keep, const float* __restrict__ vmean,
    float* __restrict__ attn_out)
{
    const int bh = blockIdx.y;
    const int b = bh >> 4, h = bh & 15;
    const int d = threadIdx.x & 63;
    const int rr = threadIdx.x >> 6;
    const float vm = vmean[bh * DK + d];
    #pragma unroll
    for (int i = 0; i < 16; ++i) {
        int row = blockIdx.x * 64 + i * 4 + rr;
        if (!keep[(size_t)bh * N + row])
            attn_out[((size_t)b * N + row) * C + h * DK + d] = vm;
    }
}

// ---------------------------------------------------------------------------
// MFMA attention on kept rows; gload staging + setprio (r10-verified).
// ---------------------------------------------------------------------------
__global__ __launch_bounds__(256) void attn_mfma(
    const u16* __restrict__ qh_, const u16* __restrict__ ql_,
    const u16* __restrict__ kh_, const u16* __restrict__ kl_,
    const u16* __restrict__ vth_, const u16* __restrict__ vtl_,
    const float* __restrict__ rowmax, const int* __restrict__ kidx,
    float* __restrict__ attn_out)
{
    __shared__ __align__(16) u16 Kh[64 * 64], Kl[64 * 64];
    __shared__ __align__(16) u16 Vh[64 * 64], Vl[64 * 64];
    __shared__ __align__(16) u16 Ph[4][16 * 64], Pl[4][16 * 64];

    const int tid = threadIdx.x, lane = tid & 63, wave = tid >> 6;
    const int wg = blockIdx.x;
    const int bh = ((wg >> 6) << 3) | (wg & 7);
    const int xblk = (wg >> 3) & 7;
    const int b = bh >> 4, h = bh & 15;
    const int q0 = xblk * 64 + wave * 16;
    const int fr = lane & 15, sl = lane >> 4;

    const bool isV = (wave >= 2);
    const u16* ksrc = (wave & 1) ? kl_ : kh_;
    const u16* vsrc = (wave & 1) ? vtl_ : vth_;
    u16* lbase = (wave == 0) ? Kh : (wave == 1) ? Kl : (wave == 2) ? Vh : Vl;
    const size_t kbase0 = (size_t)bh * N * DK;
    const size_t vbase0 = (size_t)bh * DK * N;

    const int* kix = kidx + bh * NTOP;
    const int qrow_f = kix[q0 + fr];
    int qr_o[4]; float rmax_r[4];
    #pragma unroll
    for (int r = 0; r < 4; ++r) {
        qr_o[r] = kix[q0 + sl * 4 + r];
        rmax_r[r] = rowmax[(size_t)bh * N + qr_o[r]];
    }

    short8v qfh[2], qfl[2];
    #pragma unroll
    for (int kk = 0; kk < 2; ++kk) {
        size_t qa = ((size_t)bh * N + qrow_f) * DK + kk * 32 + sl * 8;
        qfh[kk] = *(const short8v*)&qh_[qa];
        qfl[kk] = *(const short8v*)&ql_[qa];
    }

    f32x4 opv[4] = {};
    float lsum[4] = {};

    for (int kt = 0; kt < N; kt += 64) {
        __syncthreads();
        #pragma unroll
        for (int i = 0; i < 8; ++i) {
            int c = i * 64 + lane;
            int row = c >> 3, sp = c & 7;
            int gs = sp ^ (row & 7);
            const u16* g = isV ? (vsrc + vbase0 + (size_t)row * N + kt + gs * 8)
                               : (ksrc + kbase0 + (size_t)(kt + row) * DK + gs * 8);
            gload16(g, lbase + (size_t)i * 512);
        }
        __syncthreads();

        #pragma unroll
        for (int n = 0; n < 4; ++n) {
            f32x4 a = {};
            __builtin_amdgcn_s_setprio(1);
            #pragma unroll
            for (int kk = 0; kk < 2; ++kk) {
                int key = n * 16 + fr;
                int off = key * 64 + (((sl + kk * 4) ^ (key & 7)) * 8);
                short8v bh_f = *(const short8v*)&Kh[off];
                short8v bl_f = *(const short8v*)&Kl[off];
                a = __builtin_amdgcn_mfma_f32_16x16x32_bf16(qfl[kk], bh_f, a, 0, 0, 0);
                a = __builtin_amdgcn_mfma_f32_16x16x32_bf16(qfh[kk], bl_f, a, 0, 0, 0);
                a = __builtin_amdgcn_mfma_f32_16x16x32_bf16(qfh[kk], bh_f, a, 0, 0, 0);
            }
            __builtin_amdgcn_s_setprio(0);
            #pragma unroll
            for (int r = 0; r < 4; ++r) {
                float p = __expf(a[r] * SCALE - rmax_r[r]);
                lsum[r] += p;
                u16 ph = bf16_rne(p);
                u16 pl = bf16_rne(p - __uint_as_float((unsigned)ph << 16));
                int q_l = sl * 4 + r;
                int key = n * 16 + fr;
                int off = q_l * 64 + (((key >> 3) ^ (q_l & 7)) * 8) + (key & 7);
                Ph[wave][off] = ph;
                Pl[wave][off] = pl;
            }
        }

        __builtin_amdgcn_s_setprio(1);
        #pragma unroll
        for (int kk = 0; kk < 2; ++kk) {
            int aoff = fr * 64 + (((kk * 4 + sl) ^ (fr & 7)) * 8);
            short8v pah = *(const short8v*)&Ph[wave][aoff];
            short8v pal = *(const short8v*)&Pl[wave][aoff];
            #pragma unroll
            for (int n = 0; n < 4; ++n) {
                int d = n * 16 + fr;
                int voff = d * 64 + (((kk * 4 + sl) ^ (d & 7)) * 8);
                short8v vhf = *(const short8v*)&Vh[voff];
                short8v vlf = *(const short8v*)&Vl[voff];
                opv[n] = __builtin_amdgcn_mfma_f32_16x16x32_bf16(pal, vhf, opv[n], 0, 0, 0);
                opv[n] = __builtin_amdgcn_mfma_f32_16x16x32_bf16(pah, vlf, opv[n], 0, 0, 0);
                opv[n] = __builtin_amdgcn_mfma_f32_16x16x32_bf16(pah, vhf, opv[n], 0, 0, 0);
            }
        }
        __builtin_amdgcn_s_setprio(0);
    }

    #pragma unroll
    for (int w = 1; w < 16; w <<= 1)
        #pragma unroll
        for (int r = 0; r < 4; ++r)
            lsum[r] += __shfl_xor(lsum[r], w, 64);

    #pragma unroll
    for (int r = 0; r < 4; ++r) {
        const float inv = 1.0f / lsum[r];
        float* orow = attn_out + ((size_t)b * N + qr_o[r]) * C + h * DK;
        #pragma unroll
        for (int n = 0; n < 4; ++n)
            orow[n * 16 + fr] = opv[n][r] * inv;
    }
}

// ---------------------------------------------------------------------------
extern "C" void kernel_launch(void* const* d_in, const int* in_sizes, int n_in,
                              void* d_out, int out_size, void* d_ws, size_t ws_size,
                              hipStream_t stream)
{
    const float* x    = (const float*)d_in[0];
    const float* Wqkv = (const float*)d_in[1];
    const float* bqkv = (const float*)d_in[2];
    const float* Wout = (const float*)d_in[3];
    const float* bout = (const float*)d_in[4];
    float* out = (float*)d_out;

    char* ws = (char*)d_ws;
    size_t off = 0;
    auto alloc = [&](size_t bytes) -> void* {
        void* p = ws + off;
        off += (bytes + 255) & ~(size_t)255;
        return p;
    };

    const size_t BHND = (size_t)B * H * N * DK;       // 4 Mi elems
    float* q        = (float*)alloc(BHND * 4);
    float* kbuf     = (float*)alloc(BHND * 4);
    float* vbuf     = (float*)alloc(BHND * 4);
    float* attn_out = (float*)alloc((size_t)B * N * C * 4);
    u16* cvAhi = (u16*)alloc((size_t)B * N * C * 2);  // x / attn_out hi
    u16* cvAlo = (u16*)alloc((size_t)B * N * C * 2);
    u16* cvBhi = (u16*)alloc((size_t)3 * C * C * 2);
    u16* cvBlo = (u16*)alloc((size_t)3 * C * C * 2);
    u16* qhi   = (u16*)alloc(BHND * 2);
    u16* qlo   = (u16*)alloc(BHND * 2);
    u16* khi   = (u16*)alloc(BHND * 2);
    u16* klo   = (u16*)alloc(BHND * 2);
    u16* vthi  = (u16*)alloc(BHND * 2);
    u16* vtlo  = (u16*)alloc(BHND * 2);
    float* Mbuf     = (float*)alloc((size_t)B * H * N * 4);
    float* rmaxbuf  = (float*)alloc((size_t)B * H * N * 4);
    float* Mdot     = (float*)alloc((size_t)B * H * N * 4);
    int*   keep     = (int*)  alloc((size_t)B * H * N * 4);
    int*   kidx     = (int*)  alloc((size_t)B * H * NTOP * 4);
    float* vmeanbuf = (float*)alloc((size_t)B * H * DK * 4);
    float* kmeanbuf = (float*)alloc((size_t)B * H * DK * 4);
    float* partbuf  = (float*)alloc((size_t)2 * B * H * CSEG * DK * 4);
    float* thrbuf   = (float*)alloc((size_t)B * H * 4);
    int*   cntbuf   = (int*)  alloc((size_t)B * H * 4);
    int*   bandbuf  = (int*)  alloc((size_t)B * H * BAND_CAP * 4);

    const int nX = B * N * C;        // 4M
    const int nW = 3 * C * C;        // 3M
    const int nWo = C * C;           // 1M

    // 1. convert x, Wqkv to bf16 hi/lo
    convert_hilo<<<nX / 1024, 256, 0, stream>>>(x, cvAhi, cvAlo, nX);
    convert_hilo<<<nW / 1024, 256, 0, stream>>>(Wqkv, cvBhi, cvBlo, nW);

    // 2. QKV projection (2D grid — r9-verified config)
    gemm_mfma<0><<<dim3(3 * C / 128, (B * N) / 128), 256, 0, stream>>>(
        cvAhi, cvAlo, cvBhi, cvBlo, bqkv, nullptr, q, kbuf, vbuf, C);

    // 3. convert q,k hi/lo (one launch); v transposed hi/lo
    convert_hilo2<<<dim3(nX / 1024, 2), 256, 0, stream>>>(
        q, kbuf, qhi, qlo, khi, klo, nX);
    convert_hilo_T<<<dim3(N / 64, B * H), 256, 0, stream>>>(vbuf, vthi, vtlo);

    // 4. column means of v and k (fused)
    colsum_part2<<<dim3(CSEG, B * H, 2), 256, 0, stream>>>(vbuf, kbuf, partbuf);
    colsum_final2<<<B * H, 128, 0, stream>>>(partbuf, vmeanbuf, kmeanbuf);

    // 5. mean term per row: Mdot = q . kmean
    qdot_kernel<<<dim3(N / 256, B * H), 256, 0, stream>>>(q, kmeanbuf, Mdot);

    // 6. MFMA approximate row max -> M, rowmax (2D grid)
    row_stats_mfma<<<dim3(N / 128, B * H), 256, 0, stream>>>(
        qhi, qlo, khi, klo, Mdot, Mbuf, rmaxbuf);

    // 7. selection: thr (+cnt init) -> classify -> fp64 refine -> finalize
    topk_thr<<<dim3(N / 256, B * H), 256, 0, stream>>>(Mbuf, thrbuf, cntbuf);
    band_classify<<<dim3(N / 256, B * H), 256, 0, stream>>>(Mbuf, thrbuf, cntbuf, bandbuf, keep);
    refine_kernel<<<dim3(32, B * H), 256, 0, stream>>>(q, kbuf, cntbuf, bandbuf, Mbuf);
    band_finalize<<<B * H, 256, 0, stream>>>(Mbuf, cntbuf, bandbuf, keep, kidx);

    // 8. fill non-kept rows; MFMA attention on kept rows
    fill_nonkept<<<dim3(N / 64, B * H), 256, 0, stream>>>(keep, vmeanbuf, attn_out);
    attn_mfma<<<256, 256, 0, stream>>>(
        qhi, qlo, khi, klo, vthi, vtlo, rmaxbuf, kidx, attn_out);

    // 9. Output projection (2D grid)
    convert_hilo<<<nX / 1024, 256, 0, stream>>>(attn_out, cvAhi, cvAlo, nX);
    convert_hilo<<<nWo / 1024, 256, 0, stream>>>(Wout, cvBhi, cvBlo, nWo);
    gemm_mfma<1><<<dim3(C / 128, (B * N) / 128), 256, 0, stream>>>(
        cvAhi, cvAlo, cvBhi, cvBlo, bout, out, nullptr, nullptr, nullptr, C);
}

// Round 13
// 395.392 us; speedup vs baseline: 1.2281x; 1.0152x over previous
//
#include <hip/hip_runtime.h>
#include <math.h>

typedef unsigned short u16;
typedef __attribute__((ext_vector_type(8))) short short8v;  // 8 bf16 operand frag
typedef __attribute__((ext_vector_type(4))) float f32x4;    // MFMA accumulator

constexpr int B  = 2;
constexpr int N  = 2048;
constexpr int C  = 1024;
constexpr int H  = 16;
constexpr int BH = B * H;
constexpr int DK = 64;
constexpr int NTOP = 512;
constexpr float SCALE = 0.125f;  // 1/sqrt(64)
constexpr int   BAND_CAP = 1024;
constexpr float BAND_EPS = 2e-3f;   // covers 3-term split-bf16 M error (~1e-4)
constexpr int   CSEG = 16;          // column-sum segments per bh

// ---------------------------------------------------------------------------
// async global -> LDS, 16B per lane. (verified r8)
// ---------------------------------------------------------------------------
__device__ __forceinline__ void gload16(const u16* g, u16* l) {
    __builtin_amdgcn_global_load_lds(
        (const __attribute__((address_space(1))) unsigned int*)g,
        (__attribute__((address_space(3))) unsigned int*)l,
        16, 0, 0);
}

// ---------------------------------------------------------------------------
// fp32 -> bf16 hi/lo split (RNE)
// ---------------------------------------------------------------------------
__device__ __forceinline__ u16 bf16_rne(float x) {
    unsigned u = __float_as_uint(x);
    unsigned r = u + 0x7fffu + ((u >> 16) & 1u);
    return (u16)(r >> 16);
}

__global__ __launch_bounds__(256) void convert_hilo(
    const float* __restrict__ src, u16* __restrict__ hi, u16* __restrict__ lo, int n)
{
    int i = (blockIdx.x * 256 + threadIdx.x) * 4;
    if (i >= n) return;
    float4 v = *(const float4*)&src[i];
    u16 h0 = bf16_rne(v.x), h1 = bf16_rne(v.y), h2 = bf16_rne(v.z), h3 = bf16_rne(v.w);
    float f0 = __uint_as_float((unsigned)h0 << 16);
    float f1 = __uint_as_float((unsigned)h1 << 16);
    float f2 = __uint_as_float((unsigned)h2 << 16);
    float f3 = __uint_as_float((unsigned)h3 << 16);
    *(ushort4*)&hi[i] = make_ushort4(h0, h1, h2, h3);
    *(ushort4*)&lo[i] = make_ushort4(bf16_rne(v.x - f0), bf16_rne(v.y - f1),
                                     bf16_rne(v.z - f2), bf16_rne(v.w - f3));
}

// two-source variant (q and k in one launch); grid (n/1024, 2)
__global__ __launch_bounds__(256) void convert_hilo2(
    const float* __restrict__ a, const float* __restrict__ b,
    u16* __restrict__ ah, u16* __restrict__ al,
    u16* __restrict__ bh_, u16* __restrict__ bl_, int n)
{
    const float* src = blockIdx.y ? b : a;
    u16* hi = blockIdx.y ? bh_ : ah;
    u16* lo = blockIdx.y ? bl_ : al;
    int i = (blockIdx.x * 256 + threadIdx.x) * 4;
    if (i >= n) return;
    float4 v = *(const float4*)&src[i];
    u16 h0 = bf16_rne(v.x), h1 = bf16_rne(v.y), h2 = bf16_rne(v.z), h3 = bf16_rne(v.w);
    float f0 = __uint_as_float((unsigned)h0 << 16);
    float f1 = __uint_as_float((unsigned)h1 << 16);
    float f2 = __uint_as_float((unsigned)h2 << 16);
    float f3 = __uint_as_float((unsigned)h3 << 16);
    *(ushort4*)&hi[i] = make_ushort4(h0, h1, h2, h3);
    *(ushort4*)&lo[i] = make_ushort4(bf16_rne(v.x - f0), bf16_rne(v.y - f1),
                                     bf16_rne(v.z - f2), bf16_rne(v.w - f3));
}

// ---------------------------------------------------------------------------
// Transposed convert: v (bh, key, d) fp32 -> vt hi/lo (bh, d, key) bf16. (r6)
// ---------------------------------------------------------------------------
__global__ __launch_bounds__(256) void convert_hilo_T(
    const float* __restrict__ v, u16* __restrict__ th, u16* __restrict__ tl)
{
    constexpr int LS = 68;
    __shared__ u16 Sh[64 * LS], Sl[64 * LS];
    const int bh = blockIdx.y;
    const int kt = blockIdx.x * 64;
    const int tid = threadIdx.x;
    #pragma unroll
    for (int p = 0; p < 4; ++p) {
        int idx = tid * 4 + p * 1024;
        int key = idx >> 6, d = idx & 63;
        float4 x4 = *(const float4*)&v[((size_t)bh * N + kt + key) * DK + d];
        float xs[4] = {x4.x, x4.y, x4.z, x4.w};
        ushort4 hh, ll;
        u16* hp = (u16*)&hh; u16* lp = (u16*)&ll;
        #pragma unroll
        for (int j = 0; j < 4; ++j) {
            u16 h = bf16_rne(xs[j]);
            hp[j] = h;
            lp[j] = bf16_rne(xs[j] - __uint_as_float((unsigned)h << 16));
        }
        *(ushort4*)&Sh[key * LS + d] = hh;
        *(ushort4*)&Sl[key * LS + d] = ll;
    }
    __syncthreads();
    const int d = tid >> 2, seg = tid & 3;
    u16 bufh[16], bufl[16];
    #pragma unroll
    for (int i = 0; i < 16; ++i) {
        bufh[i] = Sh[(seg * 16 + i) * LS + d];
        bufl[i] = Sl[(seg * 16 + i) * LS + d];
    }
    size_t oa = ((size_t)bh * DK + d) * N + kt + seg * 16;
    *(uint4*)&th[oa] = ((uint4*)bufh)[0];
    *(uint4*)&th[oa + 8] = ((uint4*)bufh)[1];
    *(uint4*)&tl[oa] = ((uint4*)bufl)[0];
    *(uint4*)&tl[oa + 8] = ((uint4*)bufl)[1];
}

// ---------------------------------------------------------------------------
// Split-bf16 MFMA GEMM: 128x128 tile, BK=32, 4 waves, gload staging.
// 2D grid (r9/r12-verified config).
// ---------------------------------------------------------------------------
template <int MODE>
__global__ __launch_bounds__(256) void gemm_mfma(
    const u16* __restrict__ Ahi, const u16* __restrict__ Alo,
    const u16* __restrict__ Bhi, const u16* __restrict__ Blo,
    const float* __restrict__ bias, float* __restrict__ out,
    float* __restrict__ qb, float* __restrict__ kb, float* __restrict__ vb,
    int K)
{
    __shared__ __align__(16) u16 Ah[128 * 32], Al[128 * 32];
    __shared__ __align__(16) u16 Bh[128 * 32], Bl[128 * 32];

    const int tid = threadIdx.x;
    const int m0 = blockIdx.y * 128;
    const int n0 = blockIdx.x * 128;
    const int lane = tid & 63;
    const int wave = tid >> 6;
    const int wr = wave >> 1, wc = wave & 1;
    const int fr = lane & 15, sl = lane >> 4;

    const u16* gsrc = (wave == 0) ? Ahi + (size_t)m0 * K
                    : (wave == 1) ? Alo + (size_t)m0 * K
                    : (wave == 2) ? Bhi + (size_t)n0 * K
                                  : Blo + (size_t)n0 * K;
    u16* lbase = (wave == 0) ? Ah : (wave == 1) ? Al : (wave == 2) ? Bh : Bl;

    f32x4 acc[4][4] = {};

    for (int k0 = 0; k0 < K; k0 += 32) {
        __syncthreads();
        #pragma unroll
        for (int i = 0; i < 8; ++i) {
            int c = i * 64 + lane;               // chunk = 16B = 8 u16
            int row = c >> 2, sp = c & 3;
            int gs = sp ^ ((row >> 1) & 3);
            gload16(gsrc + (size_t)row * K + k0 + gs * 8, lbase + i * 512);
        }
        __syncthreads();

        short8v afh[4], afl[4], bfh[4], bfl[4];
        #pragma unroll
        for (int m = 0; m < 4; ++m) {
            int row = wr * 64 + m * 16 + fr;
            int off = row * 32 + ((sl ^ ((row >> 1) & 3)) * 8);
            afh[m] = *(const short8v*)&Ah[off];
            afl[m] = *(const short8v*)&Al[off];
        }
        #pragma unroll
        for (int n = 0; n < 4; ++n) {
            int row = wc * 64 + n * 16 + fr;
            int off = row * 32 + ((sl ^ ((row >> 1) & 3)) * 8);
            bfh[n] = *(const short8v*)&Bh[off];
            bfl[n] = *(const short8v*)&Bl[off];
        }
        #pragma unroll
        for (int m = 0; m < 4; ++m)
            #pragma unroll
            for (int n = 0; n < 4; ++n) {
                acc[m][n] = __builtin_amdgcn_mfma_f32_16x16x32_bf16(afh[m], bfh[n], acc[m][n], 0, 0, 0);
                acc[m][n] = __builtin_amdgcn_mfma_f32_16x16x32_bf16(afh[m], bfl[n], acc[m][n], 0, 0, 0);
                acc[m][n] = __builtin_amdgcn_mfma_f32_16x16x32_bf16(afl[m], bfh[n], acc[m][n], 0, 0, 0);
            }
    }

    #pragma unroll
    for (int m = 0; m < 4; ++m)
        #pragma unroll
        for (int n = 0; n < 4; ++n)
            #pragma unroll
            for (int r = 0; r < 4; ++r) {
                int grow = m0 + wr * 64 + m * 16 + sl * 4 + r;
                int gcol = n0 + wc * 64 + n * 16 + fr;
                float val = acc[m][n][r] + bias[gcol];
                if (MODE == 0) {
                    int t = gcol >> 10, h = (gcol >> 6) & 15, d = gcol & 63;
                    int bb = grow >> 11, nn = grow & (N - 1);
                    float* dst = (t == 0) ? qb : (t == 1) ? kb : vb;
                    dst[(((size_t)bb * H + h) * N + nn) * DK + d] = val;
                } else {
                    out[(size_t)grow * C + gcol] = val;
                }
            }
}

// ---------------------------------------------------------------------------
// Column sums over v and k in one launch.  grid (CSEG, B*H, 2), z: 0=v 1=k.
// ---------------------------------------------------------------------------
__global__ __launch_bounds__(256) void colsum_part2(
    const float* __restrict__ v, const float* __restrict__ k,
    float* __restrict__ partial)
{
    const int bh = blockIdx.y, seg = blockIdx.x, which = blockIdx.z;
    const float* src = which ? k : v;
    const int d = threadIdx.x & 63;
    const int sub = threadIdx.x >> 6;
    const int k0 = seg * (N / CSEG);
    float s = 0.f;
    for (int kk = sub; kk < N / CSEG; kk += 4)
        s += src[((size_t)bh * N + k0 + kk) * DK + d];
    __shared__ float part[4][64];
    part[sub][d] = s;
    __syncthreads();
    if (threadIdx.x < 64)
        partial[(((size_t)which * BH + bh) * CSEG + seg) * DK + d] =
            part[0][d] + part[1][d] + part[2][d] + part[3][d];
}

// grid (B*H), 128 threads: tid<64 -> vmean, tid>=64 -> kmean
__global__ __launch_bounds__(128) void colsum_final2(
    const float* __restrict__ partial, float* __restrict__ vmean,
    float* __restrict__ kmean)
{
    const int bh = blockIdx.x;
    const int d = threadIdx.x & 63;
    const int which = threadIdx.x >> 6;
    const float* p = partial + ((size_t)which * BH + bh) * CSEG * DK;
    float s = 0.f;
    #pragma unroll
    for (int g = 0; g < CSEG; ++g) s += p[g * DK + d];
    float* dst = which ? kmean : vmean;
    dst[bh * DK + d] = s / (float)N;
}

// ---------------------------------------------------------------------------
// Mdot[bh,row] = dot(q_row, kmean_bh)
// ---------------------------------------------------------------------------
__global__ __launch_bounds__(256) void qdot_kernel(
    const float* __restrict__ q, const float* __restrict__ kmean,
    float* __restrict__ Mdot)
{
    const int bh = blockIdx.y;
    const int row = blockIdx.x * 256 + threadIdx.x;
    __shared__ float km[DK];
    if (threadIdx.x < DK) km[threadIdx.x] = kmean[bh * DK + threadIdx.x];
    __syncthreads();
    const float* qr = &q[((size_t)bh * N + row) * DK];
    float s = 0.f;
    #pragma unroll
    for (int d4 = 0; d4 < DK; d4 += 4) {
        float4 v = *(const float4*)&qr[d4];
        s += v.x * km[d4] + v.y * km[d4 + 1] + v.z * km[d4 + 2] + v.w * km[d4 + 3];
    }
    Mdot[(size_t)bh * N + row] = s;
}

// ---------------------------------------------------------------------------
// MFMA row-max (3-term), gload staging. 2D grid (r9/r12-verified).
// ---------------------------------------------------------------------------
__global__ __launch_bounds__(256) void row_stats_mfma(
    const u16* __restrict__ qh_, const u16* __restrict__ ql_,
    const u16* __restrict__ kh_, const u16* __restrict__ kl_,
    const float* __restrict__ Mdot, float* __restrict__ Mout,
    float* __restrict__ rowmax)
{
    __shared__ __align__(16) u16 Kh[64 * 64];
    __shared__ __align__(16) u16 Kl[64 * 64];
    const int tid = threadIdx.x, lane = tid & 63, wave = tid >> 6;
    const int bh = blockIdx.y;
    const int q0 = blockIdx.x * 128 + wave * 32;
    const int fr = lane & 15, g = lane >> 4;

    const u16* gsrc = (wave & 2) ? kl_ : kh_;
    u16* lbase = (wave & 2) ? Kl : Kh;
    const int cb = (wave & 1) * 256;

    short8v qfh[2][2], qfl[2][2];
    #pragma unroll
    for (int m = 0; m < 2; ++m)
        #pragma unroll
        for (int kk = 0; kk < 2; ++kk) {
            size_t qa = ((size_t)bh * N + q0 + m * 16 + fr) * DK + kk * 32 + g * 8;
            qfh[m][kk] = *(const short8v*)&qh_[qa];
            qfl[m][kk] = *(const short8v*)&ql_[qa];
        }

    f32x4 mx[2];
    mx[0] = (f32x4){-1e30f, -1e30f, -1e30f, -1e30f};
    mx[1] = mx[0];

    for (int kt = 0; kt < N; kt += 64) {
        __syncthreads();
        #pragma unroll
        for (int i = 0; i < 4; ++i) {
            int c = cb + i * 64 + lane;
            int row = c >> 3, sp = c & 7;
            int gs = sp ^ (row & 7);
            gload16(gsrc + ((size_t)bh * N + kt + row) * DK + gs * 8,
                    lbase + (size_t)(cb + i * 64) * 8);
        }
        __syncthreads();
        short8v bfh[4][2], bfl[4][2];
        #pragma unroll
        for (int n = 0; n < 4; ++n)
            #pragma unroll
            for (int kk = 0; kk < 2; ++kk) {
                int key = n * 16 + fr;
                int off = key * 64 + (((g + kk * 4) ^ (key & 7)) * 8);
                bfh[n][kk] = *(const short8v*)&Kh[off];
                bfl[n][kk] = *(const short8v*)&Kl[off];
            }
        #pragma unroll
        for (int m = 0; m < 2; ++m)
            #pragma unroll
            for (int n = 0; n < 4; ++n) {
                f32x4 a = {};
                #pragma unroll
                for (int kk = 0; kk < 2; ++kk) {
                    a = __builtin_amdgcn_mfma_f32_16x16x32_bf16(qfl[m][kk], bfh[n][kk], a, 0, 0, 0);
                    a = __builtin_amdgcn_mfma_f32_16x16x32_bf16(qfh[m][kk], bfl[n][kk], a, 0, 0, 0);
                    a = __builtin_amdgcn_mfma_f32_16x16x32_bf16(qfh[m][kk], bfh[n][kk], a, 0, 0, 0);
                }
                #pragma unroll
                for (int r = 0; r < 4; ++r) mx[m][r] = fmaxf(mx[m][r], a[r]);
            }
    }

    #pragma unroll
    for (int w = 1; w < 16; w <<= 1)
        #pragma unroll
        for (int m = 0; m < 2; ++m)
            #pragma unroll
            for (int r = 0; r < 4; ++r)
                mx[m][r] = fmaxf(mx[m][r], __shfl_xor(mx[m][r], w, 64));

    if (fr == 0) {
        #pragma unroll
        for (int m = 0; m < 2; ++m)
            #pragma unroll
            for (int r = 0; r < 4; ++r) {
                int row = q0 + m * 16 + g * 4 + r;
                size_t idx = (size_t)bh * N + row;
                float v = mx[m][r];
                rowmax[idx] = SCALE * v;
                Mout[idx]   = SCALE * (v - Mdot[idx]);
            }
    }
}

// ---------------------------------------------------------------------------
// Selection: thr (+cnt init) -> classify -> fp64 refine -> finalize (+inv).
// ---------------------------------------------------------------------------
__global__ __launch_bounds__(256) void topk_thr(
    const float* __restrict__ Mv, float* __restrict__ thr, int* __restrict__ cnt)
{
    const int bh = blockIdx.y;
    const int qi = blockIdx.x * 256 + threadIdx.x;
    if (blockIdx.x == 0 && threadIdx.x == 0) cnt[bh] = 0;
    __shared__ float Ms[N];
    for (int e = threadIdx.x; e < N; e += 256) Ms[e] = Mv[(size_t)bh * N + e];
    __syncthreads();
    const float mq = Ms[qi];
    int rank = 0;
    for (int j = 0; j < N; ++j) {
        float mj = Ms[j];
        rank += (mj > mq) || (mj == mq && j < qi);
    }
    if (rank == NTOP - 1) thr[bh] = mq;   // smallest kept (approx boundary)
}

__global__ __launch_bounds__(256) void band_classify(
    const float* __restrict__ Mv, const float* __restrict__ thr,
    int* __restrict__ cnt, int* __restrict__ band, int* __restrict__ keep)
{
    const int bh = blockIdx.y;
    const int row = blockIdx.x * 256 + threadIdx.x;
    const float m = Mv[(size_t)bh * N + row];
    const float t = thr[bh];
    int kp;
    if (fabsf(m - t) <= BAND_EPS) {
        int pos = atomicAdd(&cnt[bh], 1);
        if (pos < BAND_CAP) band[bh * BAND_CAP + pos] = row;
        kp = 0;
    } else {
        kp = (m > t) ? 1 : 0;
    }
    keep[(size_t)bh * N + row] = kp;
}

// Block-per-candidate (strided): LDS-staged coalesced K, fp64 exact dot.
// grid (32, B*H), 256 threads.  (r10/r12-verified)
__global__ __launch_bounds__(256) void refine_kernel(
    const float* __restrict__ q, const float* __restrict__ k,
    const int* __restrict__ cnt, const int* __restrict__ band,
    float* __restrict__ Mv)
{
    constexpr int LS = 69;
    __shared__ float Ks[64 * LS];
    __shared__ float qs[DK];
    const int bh = blockIdx.y;
    const int tid = threadIdx.x;
    const int n = min(cnt[bh], BAND_CAP);
    for (int ci = blockIdx.x; ci < n; ci += 32) {
        const int row = band[bh * BAND_CAP + ci];
        __syncthreads();
        if (tid < DK) qs[tid] = q[((size_t)bh * N + row) * DK + tid];
        double mx = -1e30, sm = 0.0;
        for (int kt = 0; kt < N; kt += 64) {
            __syncthreads();
            #pragma unroll
            for (int p = 0; p < 4; ++p) {
                int idx = tid * 4 + p * 1024;
                int kr = idx >> 6, d = idx & 63;
                float4 x4 = *(const float4*)&k[((size_t)bh * N + kt + kr) * DK + d];
                Ks[kr * LS + d]     = x4.x;
                Ks[kr * LS + d + 1] = x4.y;
                Ks[kr * LS + d + 2] = x4.z;
                Ks[kr * LS + d + 3] = x4.w;
            }
            __syncthreads();
            if (tid < 64) {
                double s = 0.0;
                #pragma unroll
                for (int d = 0; d < DK; ++d)
                    s += (double)qs[d] * (double)Ks[tid * LS + d];
                mx = fmax(mx, s);
                sm += s;
            }
        }
        if (tid < 64) {
            #pragma unroll
            for (int w = 1; w < 64; w <<= 1) {
                mx = fmax(mx, __shfl_xor(mx, w, 64));
                sm += __shfl_xor(sm, w, 64);
            }
            if (tid == 0)
                Mv[(size_t)bh * N + row] = (float)((double)SCALE * (mx - sm / (double)N));
        }
    }
}

__global__ __launch_bounds__(256) void band_finalize(
    const float* __restrict__ Mv, const int* __restrict__ cnt,
    const int* __restrict__ band, int* __restrict__ keep,
    int* __restrict__ kidx, int* __restrict__ inv)
{
    __shared__ unsigned char kL[N];
    __shared__ int   bRow[BAND_CAP];
    __shared__ float bM[BAND_CAP];
    __shared__ int aW[4];
    __shared__ int scan[256];

    const int bh = blockIdx.x;
    const int tid = threadIdx.x;
    const int lane = tid & 63, wid = tid >> 6;
    const int nb = min(cnt[bh], BAND_CAP);

    int above = 0;
    #pragma unroll
    for (int w = 0; w < 8; ++w) {
        int row = w * 256 + tid;
        int kp = keep[(size_t)bh * N + row];
        kL[row] = (unsigned char)kp;
        above += kp;
    }
    #pragma unroll
    for (int w = 1; w < 64; w <<= 1) above += __shfl_xor(above, w, 64);
    if (lane == 0) aW[wid] = above;
    for (int i = tid; i < nb; i += 256) {
        int r = band[bh * BAND_CAP + i];
        bRow[i] = r;
        bM[i] = Mv[(size_t)bh * N + r];
    }
    __syncthreads();
    const int nAbove = aW[0] + aW[1] + aW[2] + aW[3];

    for (int i = tid; i < nb; i += 256) {
        const float mi = bM[i];
        const int ri = bRow[i];
        int rank = nAbove;
        for (int j = 0; j < nb; ++j) {
            float mj = bM[j];
            rank += (mj > mi) || (mj == mi && bRow[j] < ri);
        }
        int kp = (rank < NTOP) ? 1 : 0;
        kL[ri] = (unsigned char)kp;
        keep[(size_t)bh * N + ri] = kp;
    }
    __syncthreads();

    int cntL = 0;
    #pragma unroll
    for (int r = 0; r < 8; ++r) cntL += kL[tid * 8 + r];
    scan[tid] = cntL;
    __syncthreads();
    for (int s = 1; s < 256; s <<= 1) {
        int v = (tid >= s) ? scan[tid - s] : 0;
        __syncthreads();
        scan[tid] += v;
        __syncthreads();
    }
    int pos = scan[tid] - cntL;
    #pragma unroll
    for (int r = 0; r < 8; ++r) {
        int row = tid * 8 + r;
        if (kL[row]) {
            kidx[bh * NTOP + pos] = row;
            inv[(size_t)bh * N + row] = pos;
            ++pos;
        }
    }
}

// ---------------------------------------------------------------------------
// MFMA attention, split-K x2: grid 512 = half(2) x bh-xcd(256 mapping).
// Writes UNNORMALIZED partials (part_o, part_l); exact since rowmax is global.
// gload staging + setprio (r10/r12-verified core).
// ---------------------------------------------------------------------------
__global__ __launch_bounds__(256) void attn_mfma(
    const u16* __restrict__ qh_, const u16* __restrict__ ql_,
    const u16* __restrict__ kh_, const u16* __restrict__ kl_,
    const u16* __restrict__ vth_, const u16* __restrict__ vtl_,
    const float* __restrict__ rowmax, const int* __restrict__ kidx,
    float* __restrict__ part_o, float* __restrict__ part_l)
{
    __shared__ __align__(16) u16 Kh[64 * 64], Kl[64 * 64];
    __shared__ __align__(16) u16 Vh[64 * 64], Vl[64 * 64];
    __shared__ __align__(16) u16 Ph[4][16 * 64], Pl[4][16 * 64];

    const int tid = threadIdx.x, lane = tid & 63, wave = tid >> 6;
    const int wg = blockIdx.x & 255;
    const int half = blockIdx.x >> 8;
    const int ks0 = half * (N / 2);
    const int bh = ((wg >> 6) << 3) | (wg & 7);
    const int xblk = (wg >> 3) & 7;
    const int q0 = xblk * 64 + wave * 16;
    const int fr = lane & 15, sl = lane >> 4;

    const bool isV = (wave >= 2);
    const u16* ksrc = (wave & 1) ? kl_ : kh_;
    const u16* vsrc = (wave & 1) ? vtl_ : vth_;
    u16* lbase = (wave == 0) ? Kh : (wave == 1) ? Kl : (wave == 2) ? Vh : Vl;
    const size_t kbase0 = (size_t)bh * N * DK;
    const size_t vbase0 = (size_t)bh * DK * N;

    const int* kix = kidx + bh * NTOP;
    const int qrow_f = kix[q0 + fr];
    float rmax_r[4];
    #pragma unroll
    for (int r = 0; r < 4; ++r)
        rmax_r[r] = rowmax[(size_t)bh * N + kix[q0 + sl * 4 + r]];

    short8v qfh[2], qfl[2];
    #pragma unroll
    for (int kk = 0; kk < 2; ++kk) {
        size_t qa = ((size_t)bh * N + qrow_f) * DK + kk * 32 + sl * 8;
        qfh[kk] = *(const short8v*)&qh_[qa];
        qfl[kk] = *(const short8v*)&ql_[qa];
    }

    f32x4 opv[4] = {};
    float lsum[4] = {};

    for (int kt = ks0; kt < ks0 + N / 2; kt += 64) {
        __syncthreads();
        #pragma unroll
        for (int i = 0; i < 8; ++i) {
            int c = i * 64 + lane;
            int row = c >> 3, sp = c & 7;
            int gs = sp ^ (row & 7);
            const u16* g = isV ? (vsrc + vbase0 + (size_t)row * N + kt + gs * 8)
                               : (ksrc + kbase0 + (size_t)(kt + row) * DK + gs * 8);
            gload16(g, lbase + (size_t)i * 512);
        }
        __syncthreads();

        #pragma unroll
        for (int n = 0; n < 4; ++n) {
            f32x4 a = {};
            __builtin_amdgcn_s_setprio(1);
            #pragma unroll
            for (int kk = 0; kk < 2; ++kk) {
                int key = n * 16 + fr;
                int off = key * 64 + (((sl + kk * 4) ^ (key & 7)) * 8);
                short8v bh_f = *(const short8v*)&Kh[off];
                short8v bl_f = *(const short8v*)&Kl[off];
                a = __builtin_amdgcn_mfma_f32_16x16x32_bf16(qfl[kk], bh_f, a, 0, 0, 0);
                a = __builtin_amdgcn_mfma_f32_16x16x32_bf16(qfh[kk], bl_f, a, 0, 0, 0);
                a = __builtin_amdgcn_mfma_f32_16x16x32_bf16(qfh[kk], bh_f, a, 0, 0, 0);
            }
            __builtin_amdgcn_s_setprio(0);
            #pragma unroll
            for (int r = 0; r < 4; ++r) {
                float p = __expf(a[r] * SCALE - rmax_r[r]);
                lsum[r] += p;
                u16 ph = bf16_rne(p);
                u16 pl = bf16_rne(p - __uint_as_float((unsigned)ph << 16));
                int q_l = sl * 4 + r;
                int key = n * 16 + fr;
                int off = q_l * 64 + (((key >> 3) ^ (q_l & 7)) * 8) + (key & 7);
                Ph[wave][off] = ph;
                Pl[wave][off] = pl;
            }
        }

        __builtin_amdgcn_s_setprio(1);
        #pragma unroll
        for (int kk = 0; kk < 2; ++kk) {
            int aoff = fr * 64 + (((kk * 4 + sl) ^ (fr & 7)) * 8);
            short8v pah = *(const short8v*)&Ph[wave][aoff];
            short8v pal = *(const short8v*)&Pl[wave][aoff];
            #pragma unroll
            for (int n = 0; n < 4; ++n) {
                int d = n * 16 + fr;
                int voff = d * 64 + (((kk * 4 + sl) ^ (d & 7)) * 8);
                short8v vhf = *(const short8v*)&Vh[voff];
                short8v vlf = *(const short8v*)&Vl[voff];
                opv[n] = __builtin_amdgcn_mfma_f32_16x16x32_bf16(pal, vhf, opv[n], 0, 0, 0);
                opv[n] = __builtin_amdgcn_mfma_f32_16x16x32_bf16(pah, vlf, opv[n], 0, 0, 0);
                opv[n] = __builtin_amdgcn_mfma_f32_16x16x32_bf16(pah, vhf, opv[n], 0, 0, 0);
            }
        }
        __builtin_amdgcn_s_setprio(0);
    }

    #pragma unroll
    for (int w = 1; w < 16; w <<= 1)
        #pragma unroll
        for (int r = 0; r < 4; ++r)
            lsum[r] += __shfl_xor(lsum[r], w, 64);

    const size_t pbase = ((size_t)half * BH + bh) * NTOP;
    #pragma unroll
    for (int r = 0; r < 4; ++r) {
        const int pos = q0 + sl * 4 + r;
        if (fr == 0) part_l[pbase + pos] = lsum[r];
        #pragma unroll
        for (int n = 0; n < 4; ++n)
            part_o[(pbase + pos) * DK + n * 16 + fr] = opv[n][r];
    }
}

// ---------------------------------------------------------------------------
// Epilogue: kept rows -> (o1+o2)/(l1+l2); non-kept -> vmean. grid (16, B*H).
// Replaces fill_nonkept + merge.
// ---------------------------------------------------------------------------
__global__ __launch_bounds__(256) void attn_epilogue(
    const float* __restrict__ part_o, const float* __restrict__ part_l,
    const int* __restrict__ keep, const int* __restrict__ inv,
    const float* __restrict__ vmean, float* __restrict__ attn_out)
{
    const int bh = blockIdx.y;
    const int b = bh >> 4, h = bh & 15;
    const int r0 = blockIdx.x * 128;
    const int tid = threadIdx.x;
    for (int e = tid; e < 128 * DK; e += 256) {
        const int row = r0 + (e >> 6);
        const int d = e & 63;
        float o;
        if (keep[(size_t)bh * N + row]) {
            const int pos = inv[(size_t)bh * N + row];
            const size_t p0 = ((size_t)0 * BH + bh) * NTOP + pos;
            const size_t p1 = ((size_t)1 * BH + bh) * NTOP + pos;
            const float l = part_l[p0] + part_l[p1];
            o = (part_o[p0 * DK + d] + part_o[p1 * DK + d]) / l;
        } else {
            o = vmean[bh * DK + d];
        }
        attn_out[((size_t)b * N + row) * C + h * DK + d] = o;
    }
}

// ---------------------------------------------------------------------------
extern "C" void kernel_launch(void* const* d_in, const int* in_sizes, int n_in,
                              void* d_out, int out_size, void* d_ws, size_t ws_size,
                              hipStream_t stream)
{
    const float* x    = (const float*)d_in[0];
    const float* Wqkv = (const float*)d_in[1];
    const float* bqkv = (const float*)d_in[2];
    const float* Wout = (const float*)d_in[3];
    const float* bout = (const float*)d_in[4];
    float* out = (float*)d_out;

    char* ws = (char*)d_ws;
    size_t off = 0;
    auto alloc = [&](size_t bytes) -> void* {
        void* p = ws + off;
        off += (bytes + 255) & ~(size_t)255;
        return p;
    };

    const size_t BHND = (size_t)B * H * N * DK;       // 4 Mi elems
    float* q        = (float*)alloc(BHND * 4);
    float* kbuf     = (float*)alloc(BHND * 4);
    float* vbuf     = (float*)alloc(BHND * 4);
    float* attn_out = (float*)alloc((size_t)B * N * C * 4);
    u16* cvAhi = (u16*)alloc((size_t)B * N * C * 2);  // x / attn_out hi
    u16* cvAlo = (u16*)alloc((size_t)B * N * C * 2);
    u16* cvBhi = (u16*)alloc((size_t)3 * C * C * 2);
    u16* cvBlo = (u16*)alloc((size_t)3 * C * C * 2);
    u16* qhi   = (u16*)alloc(BHND * 2);
    u16* qlo   = (u16*)alloc(BHND * 2);
    u16* khi   = (u16*)alloc(BHND * 2);
    u16* klo   = (u16*)alloc(BHND * 2);
    u16* vthi  = (u16*)alloc(BHND * 2);
    u16* vtlo  = (u16*)alloc(BHND * 2);
    float* Mbuf     = (float*)alloc((size_t)BH * N * 4);
    float* rmaxbuf  = (float*)alloc((size_t)BH * N * 4);
    float* Mdot     = (float*)alloc((size_t)BH * N * 4);
    int*   keep     = (int*)  alloc((size_t)BH * N * 4);
    int*   inv      = (int*)  alloc((size_t)BH * N * 4);
    int*   kidx     = (int*)  alloc((size_t)BH * NTOP * 4);
    float* vmeanbuf = (float*)alloc((size_t)BH * DK * 4);
    float* kmeanbuf = (float*)alloc((size_t)BH * DK * 4);
    float* partbuf  = (float*)alloc((size_t)2 * BH * CSEG * DK * 4);
    float* thrbuf   = (float*)alloc((size_t)BH * 4);
    int*   cntbuf   = (int*)  alloc((size_t)BH * 4);
    int*   bandbuf  = (int*)  alloc((size_t)BH * BAND_CAP * 4);
    float* part_o   = (float*)alloc((size_t)2 * BH * NTOP * DK * 4);  // 8 MB
    float* part_l   = (float*)alloc((size_t)2 * BH * NTOP * 4);

    const int nX = B * N * C;        // 4M
    const int nW = 3 * C * C;        // 3M
    const int nWo = C * C;           // 1M

    // 1. convert x, Wqkv to bf16 hi/lo
    convert_hilo<<<nX / 1024, 256, 0, stream>>>(x, cvAhi, cvAlo, nX);
    convert_hilo<<<nW / 1024, 256, 0, stream>>>(Wqkv, cvBhi, cvBlo, nW);

    // 2. QKV projection (2D grid — r9/r12-verified config)
    gemm_mfma<0><<<dim3(3 * C / 128, (B * N) / 128), 256, 0, stream>>>(
        cvAhi, cvAlo, cvBhi, cvBlo, bqkv, nullptr, q, kbuf, vbuf, C);

    // 3. convert q,k hi/lo (one launch); v transposed hi/lo
    convert_hilo2<<<dim3(nX / 1024, 2), 256, 0, stream>>>(
        q, kbuf, qhi, qlo, khi, klo, nX);
    convert_hilo_T<<<dim3(N / 64, BH), 256, 0, stream>>>(vbuf, vthi, vtlo);

    // 4. column means of v and k (fused)
    colsum_part2<<<dim3(CSEG, BH, 2), 256, 0, stream>>>(vbuf, kbuf, partbuf);
    colsum_final2<<<BH, 128, 0, stream>>>(partbuf, vmeanbuf, kmeanbuf);

    // 5. mean term per row: Mdot = q . kmean
    qdot_kernel<<<dim3(N / 256, BH), 256, 0, stream>>>(q, kmeanbuf, Mdot);

    // 6. MFMA approximate row max -> M, rowmax (2D grid)
    row_stats_mfma<<<dim3(N / 128, BH), 256, 0, stream>>>(
        qhi, qlo, khi, klo, Mdot, Mbuf, rmaxbuf);

    // 7. selection: thr (+cnt init) -> classify -> fp64 refine -> finalize(+inv)
    topk_thr<<<dim3(N / 256, BH), 256, 0, stream>>>(Mbuf, thrbuf, cntbuf);
    band_classify<<<dim3(N / 256, BH), 256, 0, stream>>>(Mbuf, thrbuf, cntbuf, bandbuf, keep);
    refine_kernel<<<dim3(32, BH), 256, 0, stream>>>(q, kbuf, cntbuf, bandbuf, Mbuf);
    band_finalize<<<BH, 256, 0, stream>>>(Mbuf, cntbuf, bandbuf, keep, kidx, inv);

    // 8. split-K MFMA attention (partials) + fused epilogue (merge + vmean fill)
    attn_mfma<<<512, 256, 0, stream>>>(
        qhi, qlo, khi, klo, vthi, vtlo, rmaxbuf, kidx, part_o, part_l);
    attn_epilogue<<<dim3(16, BH), 256, 0, stream>>>(
        part_o, part_l, keep, inv, vmeanbuf, attn_out);

    // 9. Output projection (2D grid)
    convert_hilo<<<nX / 1024, 256, 0, stream>>>(attn_out, cvAhi, cvAlo, nX);
    convert_hilo<<<nWo / 1024, 256, 0, stream>>>(Wout, cvBhi, cvBlo, nWo);
    gemm_mfma<1><<<dim3(C / 128, (B * N) / 128), 256, 0, stream>>>(
        cvAhi, cvAlo, cvBhi, cvBlo, bout, out, nullptr, nullptr, nullptr, C);
}

// Round 14
// 373.617 us; speedup vs baseline: 1.2997x; 1.0583x over previous
//
#include <hip/hip_runtime.h>
#include <math.h>

typedef unsigned short u16;
typedef __attribute__((ext_vector_type(8))) short short8v;  // 8 bf16 operand frag
typedef __attribute__((ext_vector_type(4))) float f32x4;    // MFMA accumulator

constexpr int B  = 2;
constexpr int N  = 2048;
constexpr int C  = 1024;
constexpr int H  = 16;
constexpr int BH = B * H;
constexpr int DK = 64;
constexpr int NTOP = 512;
constexpr float SCALE = 0.125f;  // 1/sqrt(64)
constexpr int   BAND_CAP = 1024;
constexpr float BAND_EPS = 2e-3f;   // covers 3-term split-bf16 M error (~1e-4)
constexpr int   CSEG = 16;          // column-sum segments per bh

// ---------------------------------------------------------------------------
// async global -> LDS, 16B per lane. (verified r8)
// ---------------------------------------------------------------------------
__device__ __forceinline__ void gload16(const u16* g, u16* l) {
    __builtin_amdgcn_global_load_lds(
        (const __attribute__((address_space(1))) unsigned int*)g,
        (__attribute__((address_space(3))) unsigned int*)l,
        16, 0, 0);
}

// ---------------------------------------------------------------------------
// fp32 -> bf16 hi/lo split (RNE)
// ---------------------------------------------------------------------------
__device__ __forceinline__ u16 bf16_rne(float x) {
    unsigned u = __float_as_uint(x);
    unsigned r = u + 0x7fffu + ((u >> 16) & 1u);
    return (u16)(r >> 16);
}

// one launch converts x (4096 blk), Wqkv (3072 blk), Wout (1024 blk)
__global__ __launch_bounds__(256) void convert_hilo3(
    const float* __restrict__ x, const float* __restrict__ wqkv,
    const float* __restrict__ wout,
    u16* __restrict__ xh, u16* __restrict__ xl,
    u16* __restrict__ wh, u16* __restrict__ wl,
    u16* __restrict__ woh, u16* __restrict__ wol)
{
    const int bid = blockIdx.x;
    const float* src; u16* hi; u16* lo; int base;
    if (bid < 4096)      { src = x;    hi = xh;  lo = xl;  base = bid; }
    else if (bid < 7168) { src = wqkv; hi = wh;  lo = wl;  base = bid - 4096; }
    else                 { src = wout; hi = woh; lo = wol; base = bid - 7168; }
    int i = (base * 256 + threadIdx.x) * 4;
    float4 v = *(const float4*)&src[i];
    u16 h0 = bf16_rne(v.x), h1 = bf16_rne(v.y), h2 = bf16_rne(v.z), h3 = bf16_rne(v.w);
    float f0 = __uint_as_float((unsigned)h0 << 16);
    float f1 = __uint_as_float((unsigned)h1 << 16);
    float f2 = __uint_as_float((unsigned)h2 << 16);
    float f3 = __uint_as_float((unsigned)h3 << 16);
    *(ushort4*)&hi[i] = make_ushort4(h0, h1, h2, h3);
    *(ushort4*)&lo[i] = make_ushort4(bf16_rne(v.x - f0), bf16_rne(v.y - f1),
                                     bf16_rne(v.z - f2), bf16_rne(v.w - f3));
}

// two-source variant (q and k in one launch); grid (n/1024, 2)
__global__ __launch_bounds__(256) void convert_hilo2(
    const float* __restrict__ a, const float* __restrict__ b,
    u16* __restrict__ ah, u16* __restrict__ al,
    u16* __restrict__ bh_, u16* __restrict__ bl_, int n)
{
    const float* src = blockIdx.y ? b : a;
    u16* hi = blockIdx.y ? bh_ : ah;
    u16* lo = blockIdx.y ? bl_ : al;
    int i = (blockIdx.x * 256 + threadIdx.x) * 4;
    if (i >= n) return;
    float4 v = *(const float4*)&src[i];
    u16 h0 = bf16_rne(v.x), h1 = bf16_rne(v.y), h2 = bf16_rne(v.z), h3 = bf16_rne(v.w);
    float f0 = __uint_as_float((unsigned)h0 << 16);
    float f1 = __uint_as_float((unsigned)h1 << 16);
    float f2 = __uint_as_float((unsigned)h2 << 16);
    float f3 = __uint_as_float((unsigned)h3 << 16);
    *(ushort4*)&hi[i] = make_ushort4(h0, h1, h2, h3);
    *(ushort4*)&lo[i] = make_ushort4(bf16_rne(v.x - f0), bf16_rne(v.y - f1),
                                     bf16_rne(v.z - f2), bf16_rne(v.w - f3));
}

// ---------------------------------------------------------------------------
// Transposed convert: v (bh, key, d) fp32 -> vt hi/lo (bh, d, key) bf16. (r6)
// ---------------------------------------------------------------------------
__global__ __launch_bounds__(256) void convert_hilo_T(
    const float* __restrict__ v, u16* __restrict__ th, u16* __restrict__ tl)
{
    constexpr int LS = 68;
    __shared__ u16 Sh[64 * LS], Sl[64 * LS];
    const int bh = blockIdx.y;
    const int kt = blockIdx.x * 64;
    const int tid = threadIdx.x;
    #pragma unroll
    for (int p = 0; p < 4; ++p) {
        int idx = tid * 4 + p * 1024;
        int key = idx >> 6, d = idx & 63;
        float4 x4 = *(const float4*)&v[((size_t)bh * N + kt + key) * DK + d];
        float xs[4] = {x4.x, x4.y, x4.z, x4.w};
        ushort4 hh, ll;
        u16* hp = (u16*)&hh; u16* lp = (u16*)&ll;
        #pragma unroll
        for (int j = 0; j < 4; ++j) {
            u16 h = bf16_rne(xs[j]);
            hp[j] = h;
            lp[j] = bf16_rne(xs[j] - __uint_as_float((unsigned)h << 16));
        }
        *(ushort4*)&Sh[key * LS + d] = hh;
        *(ushort4*)&Sl[key * LS + d] = ll;
    }
    __syncthreads();
    const int d = tid >> 2, seg = tid & 3;
    u16 bufh[16], bufl[16];
    #pragma unroll
    for (int i = 0; i < 16; ++i) {
        bufh[i] = Sh[(seg * 16 + i) * LS + d];
        bufl[i] = Sl[(seg * 16 + i) * LS + d];
    }
    size_t oa = ((size_t)bh * DK + d) * N + kt + seg * 16;
    *(uint4*)&th[oa] = ((uint4*)bufh)[0];
    *(uint4*)&th[oa + 8] = ((uint4*)bufh)[1];
    *(uint4*)&tl[oa] = ((uint4*)bufl)[0];
    *(uint4*)&tl[oa + 8] = ((uint4*)bufl)[1];
}

// ---------------------------------------------------------------------------
// Split-bf16 MFMA GEMM: 128x128 tile, BK=32, 4 waves, gload staging.
// 2D grid (r9/r12-verified config).
// ---------------------------------------------------------------------------
template <int MODE>
__global__ __launch_bounds__(256) void gemm_mfma(
    const u16* __restrict__ Ahi, const u16* __restrict__ Alo,
    const u16* __restrict__ Bhi, const u16* __restrict__ Blo,
    const float* __restrict__ bias, float* __restrict__ out,
    float* __restrict__ qb, float* __restrict__ kb, float* __restrict__ vb,
    int K)
{
    __shared__ __align__(16) u16 Ah[128 * 32], Al[128 * 32];
    __shared__ __align__(16) u16 Bh[128 * 32], Bl[128 * 32];

    const int tid = threadIdx.x;
    const int m0 = blockIdx.y * 128;
    const int n0 = blockIdx.x * 128;
    const int lane = tid & 63;
    const int wave = tid >> 6;
    const int wr = wave >> 1, wc = wave & 1;
    const int fr = lane & 15, sl = lane >> 4;

    const u16* gsrc = (wave == 0) ? Ahi + (size_t)m0 * K
                    : (wave == 1) ? Alo + (size_t)m0 * K
                    : (wave == 2) ? Bhi + (size_t)n0 * K
                                  : Blo + (size_t)n0 * K;
    u16* lbase = (wave == 0) ? Ah : (wave == 1) ? Al : (wave == 2) ? Bh : Bl;

    f32x4 acc[4][4] = {};

    for (int k0 = 0; k0 < K; k0 += 32) {
        __syncthreads();
        #pragma unroll
        for (int i = 0; i < 8; ++i) {
            int c = i * 64 + lane;               // chunk = 16B = 8 u16
            int row = c >> 2, sp = c & 3;
            int gs = sp ^ ((row >> 1) & 3);
            gload16(gsrc + (size_t)row * K + k0 + gs * 8, lbase + i * 512);
        }
        __syncthreads();

        short8v afh[4], afl[4], bfh[4], bfl[4];
        #pragma unroll
        for (int m = 0; m < 4; ++m) {
            int row = wr * 64 + m * 16 + fr;
            int off = row * 32 + ((sl ^ ((row >> 1) & 3)) * 8);
            afh[m] = *(const short8v*)&Ah[off];
            afl[m] = *(const short8v*)&Al[off];
        }
        #pragma unroll
        for (int n = 0; n < 4; ++n) {
            int row = wc * 64 + n * 16 + fr;
            int off = row * 32 + ((sl ^ ((row >> 1) & 3)) * 8);
            bfh[n] = *(const short8v*)&Bh[off];
            bfl[n] = *(const short8v*)&Bl[off];
        }
        #pragma unroll
        for (int m = 0; m < 4; ++m)
            #pragma unroll
            for (int n = 0; n < 4; ++n) {
                acc[m][n] = __builtin_amdgcn_mfma_f32_16x16x32_bf16(afh[m], bfh[n], acc[m][n], 0, 0, 0);
                acc[m][n] = __builtin_amdgcn_mfma_f32_16x16x32_bf16(afh[m], bfl[n], acc[m][n], 0, 0, 0);
                acc[m][n] = __builtin_amdgcn_mfma_f32_16x16x32_bf16(afl[m], bfh[n], acc[m][n], 0, 0, 0);
            }
    }

    #pragma unroll
    for (int m = 0; m < 4; ++m)
        #pragma unroll
        for (int n = 0; n < 4; ++n)
            #pragma unroll
            for (int r = 0; r < 4; ++r) {
                int grow = m0 + wr * 64 + m * 16 + sl * 4 + r;
                int gcol = n0 + wc * 64 + n * 16 + fr;
                float val = acc[m][n][r] + bias[gcol];
                if (MODE == 0) {
                    int t = gcol >> 10, h = (gcol >> 6) & 15, d = gcol & 63;
                    int bb = grow >> 11, nn = grow & (N - 1);
                    float* dst = (t == 0) ? qb : (t == 1) ? kb : vb;
                    dst[(((size_t)bb * H + h) * N + nn) * DK + d] = val;
                } else {
                    out[(size_t)grow * C + gcol] = val;
                }
            }
}

// ---------------------------------------------------------------------------
// Column sums over v and k in one launch.  grid (CSEG, B*H, 2), z: 0=v 1=k.
// ---------------------------------------------------------------------------
__global__ __launch_bounds__(256) void colsum_part2(
    const float* __restrict__ v, const float* __restrict__ k,
    float* __restrict__ partial)
{
    const int bh = blockIdx.y, seg = blockIdx.x, which = blockIdx.z;
    const float* src = which ? k : v;
    const int d = threadIdx.x & 63;
    const int sub = threadIdx.x >> 6;
    const int k0 = seg * (N / CSEG);
    float s = 0.f;
    for (int kk = sub; kk < N / CSEG; kk += 4)
        s += src[((size_t)bh * N + k0 + kk) * DK + d];
    __shared__ float part[4][64];
    part[sub][d] = s;
    __syncthreads();
    if (threadIdx.x < 64)
        partial[(((size_t)which * BH + bh) * CSEG + seg) * DK + d] =
            part[0][d] + part[1][d] + part[2][d] + part[3][d];
}

// ---------------------------------------------------------------------------
// Mdot[bh,row] = dot(q_row, kmean_bh); kmean reduced from partials in-block.
// ---------------------------------------------------------------------------
__global__ __launch_bounds__(256) void qdot_kernel(
    const float* __restrict__ q, const float* __restrict__ partial,
    float* __restrict__ Mdot)
{
    const int bh = blockIdx.y;
    const int row = blockIdx.x * 256 + threadIdx.x;
    __shared__ float km[DK];
    if (threadIdx.x < DK) {
        const float* p = partial + ((size_t)1 * BH + bh) * CSEG * DK;
        float s = 0.f;
        #pragma unroll
        for (int g = 0; g < CSEG; ++g) s += p[g * DK + threadIdx.x];
        km[threadIdx.x] = s / (float)N;
    }
    __syncthreads();
    const float* qr = &q[((size_t)bh * N + row) * DK];
    float s = 0.f;
    #pragma unroll
    for (int d4 = 0; d4 < DK; d4 += 4) {
        float4 v = *(const float4*)&qr[d4];
        s += v.x * km[d4] + v.y * km[d4 + 1] + v.z * km[d4 + 2] + v.w * km[d4 + 3];
    }
    Mdot[(size_t)bh * N + row] = s;
}

// ---------------------------------------------------------------------------
// MFMA row-max (3-term), gload staging. 2D grid (r9/r12-verified).
// ---------------------------------------------------------------------------
__global__ __launch_bounds__(256) void row_stats_mfma(
    const u16* __restrict__ qh_, const u16* __restrict__ ql_,
    const u16* __restrict__ kh_, const u16* __restrict__ kl_,
    const float* __restrict__ Mdot, float* __restrict__ Mout,
    float* __restrict__ rowmax)
{
    __shared__ __align__(16) u16 Kh[64 * 64];
    __shared__ __align__(16) u16 Kl[64 * 64];
    const int tid = threadIdx.x, lane = tid & 63, wave = tid >> 6;
    const int bh = blockIdx.y;
    const int q0 = blockIdx.x * 128 + wave * 32;
    const int fr = lane & 15, g = lane >> 4;

    const u16* gsrc = (wave & 2) ? kl_ : kh_;
    u16* lbase = (wave & 2) ? Kl : Kh;
    const int cb = (wave & 1) * 256;

    short8v qfh[2][2], qfl[2][2];
    #pragma unroll
    for (int m = 0; m < 2; ++m)
        #pragma unroll
        for (int kk = 0; kk < 2; ++kk) {
            size_t qa = ((size_t)bh * N + q0 + m * 16 + fr) * DK + kk * 32 + g * 8;
            qfh[m][kk] = *(const short8v*)&qh_[qa];
            qfl[m][kk] = *(const short8v*)&ql_[qa];
        }

    f32x4 mx[2];
    mx[0] = (f32x4){-1e30f, -1e30f, -1e30f, -1e30f};
    mx[1] = mx[0];

    for (int kt = 0; kt < N; kt += 64) {
        __syncthreads();
        #pragma unroll
        for (int i = 0; i < 4; ++i) {
            int c = cb + i * 64 + lane;
            int row = c >> 3, sp = c & 7;
            int gs = sp ^ (row & 7);
            gload16(gsrc + ((size_t)bh * N + kt + row) * DK + gs * 8,
                    lbase + (size_t)(cb + i * 64) * 8);
        }
        __syncthreads();
        short8v bfh[4][2], bfl[4][2];
        #pragma unroll
        for (int n = 0; n < 4; ++n)
            #pragma unroll
            for (int kk = 0; kk < 2; ++kk) {
                int key = n * 16 + fr;
                int off = key * 64 + (((g + kk * 4) ^ (key & 7)) * 8);
                bfh[n][kk] = *(const short8v*)&Kh[off];
                bfl[n][kk] = *(const short8v*)&Kl[off];
            }
        #pragma unroll
        for (int m = 0; m < 2; ++m)
            #pragma unroll
            for (int n = 0; n < 4; ++n) {
                f32x4 a = {};
                #pragma unroll
                for (int kk = 0; kk < 2; ++kk) {
                    a = __builtin_amdgcn_mfma_f32_16x16x32_bf16(qfl[m][kk], bfh[n][kk], a, 0, 0, 0);
                    a = __builtin_amdgcn_mfma_f32_16x16x32_bf16(qfh[m][kk], bfl[n][kk], a, 0, 0, 0);
                    a = __builtin_amdgcn_mfma_f32_16x16x32_bf16(qfh[m][kk], bfh[n][kk], a, 0, 0, 0);
                }
                #pragma unroll
                for (int r = 0; r < 4; ++r) mx[m][r] = fmaxf(mx[m][r], a[r]);
            }
    }

    #pragma unroll
    for (int w = 1; w < 16; w <<= 1)
        #pragma unroll
        for (int m = 0; m < 2; ++m)
            #pragma unroll
            for (int r = 0; r < 4; ++r)
                mx[m][r] = fmaxf(mx[m][r], __shfl_xor(mx[m][r], w, 64));

    if (fr == 0) {
        #pragma unroll
        for (int m = 0; m < 2; ++m)
            #pragma unroll
            for (int r = 0; r < 4; ++r) {
                int row = q0 + m * 16 + g * 4 + r;
                size_t idx = (size_t)bh * N + row;
                float v = mx[m][r];
                rowmax[idx] = SCALE * v;
                Mout[idx]   = SCALE * (v - Mdot[idx]);
            }
    }
}

// ---------------------------------------------------------------------------
// Selection: thr (+cnt init) -> classify -> fp64 refine -> finalize (+inv).
// ---------------------------------------------------------------------------
__global__ __launch_bounds__(256) void topk_thr(
    const float* __restrict__ Mv, float* __restrict__ thr, int* __restrict__ cnt)
{
    const int bh = blockIdx.y;
    const int qi = blockIdx.x * 256 + threadIdx.x;
    if (blockIdx.x == 0 && threadIdx.x == 0) cnt[bh] = 0;
    __shared__ float Ms[N];
    for (int e = threadIdx.x; e < N; e += 256) Ms[e] = Mv[(size_t)bh * N + e];
    __syncthreads();
    const float mq = Ms[qi];
    int rank = 0;
    for (int j = 0; j < N; ++j) {
        float mj = Ms[j];
        rank += (mj > mq) || (mj == mq && j < qi);
    }
    if (rank == NTOP - 1) thr[bh] = mq;   // smallest kept (approx boundary)
}

__global__ __launch_bounds__(256) void band_classify(
    const float* __restrict__ Mv, const float* __restrict__ thr,
    int* __restrict__ cnt, int* __restrict__ band, int* __restrict__ keep)
{
    const int bh = blockIdx.y;
    const int row = blockIdx.x * 256 + threadIdx.x;
    const float m = Mv[(size_t)bh * N + row];
    const float t = thr[bh];
    int kp;
    if (fabsf(m - t) <= BAND_EPS) {
        int pos = atomicAdd(&cnt[bh], 1);
        if (pos < BAND_CAP) band[bh * BAND_CAP + pos] = row;
        kp = 0;
    } else {
        kp = (m > t) ? 1 : 0;
    }
    keep[(size_t)bh * N + row] = kp;
}

// Block-per-candidate (strided): LDS-staged coalesced K, fp64 exact dot.
// grid (32, B*H), 256 threads.  (r10/r12-verified)
__global__ __launch_bounds__(256) void refine_kernel(
    const float* __restrict__ q, const float* __restrict__ k,
    const int* __restrict__ cnt, const int* __restrict__ band,
    float* __restrict__ Mv)
{
    constexpr int LS = 69;
    __shared__ float Ks[64 * LS];
    __shared__ float qs[DK];
    const int bh = blockIdx.y;
    const int tid = threadIdx.x;
    const int n = min(cnt[bh], BAND_CAP);
    for (int ci = blockIdx.x; ci < n; ci += 32) {
        const int row = band[bh * BAND_CAP + ci];
        __syncthreads();
        if (tid < DK) qs[tid] = q[((size_t)bh * N + row) * DK + tid];
        double mx = -1e30, sm = 0.0;
        for (int kt = 0; kt < N; kt += 64) {
            __syncthreads();
            #pragma unroll
            for (int p = 0; p < 4; ++p) {
                int idx = tid * 4 + p * 1024;
                int kr = idx >> 6, d = idx & 63;
                float4 x4 = *(const float4*)&k[((size_t)bh * N + kt + kr) * DK + d];
                Ks[kr * LS + d]     = x4.x;
                Ks[kr * LS + d + 1] = x4.y;
                Ks[kr * LS + d + 2] = x4.z;
                Ks[kr * LS + d + 3] = x4.w;
            }
            __syncthreads();
            if (tid < 64) {
                double s = 0.0;
                #pragma unroll
                for (int d = 0; d < DK; ++d)
                    s += (double)qs[d] * (double)Ks[tid * LS + d];
                mx = fmax(mx, s);
                sm += s;
            }
        }
        if (tid < 64) {
            #pragma unroll
            for (int w = 1; w < 64; w <<= 1) {
                mx = fmax(mx, __shfl_xor(mx, w, 64));
                sm += __shfl_xor(sm, w, 64);
            }
            if (tid == 0)
                Mv[(size_t)bh * N + row] = (float)((double)SCALE * (mx - sm / (double)N));
        }
    }
}

__global__ __launch_bounds__(256) void band_finalize(
    const float* __restrict__ Mv, const int* __restrict__ cnt,
    const int* __restrict__ band, int* __restrict__ keep,
    int* __restrict__ kidx, int* __restrict__ inv)
{
    __shared__ unsigned char kL[N];
    __shared__ int   bRow[BAND_CAP];
    __shared__ float bM[BAND_CAP];
    __shared__ int aW[4];
    __shared__ int scan[256];

    const int bh = blockIdx.x;
    const int tid = threadIdx.x;
    const int lane = tid & 63, wid = tid >> 6;
    const int nb = min(cnt[bh], BAND_CAP);

    int above = 0;
    #pragma unroll
    for (int w = 0; w < 8; ++w) {
        int row = w * 256 + tid;
        int kp = keep[(size_t)bh * N + row];
        kL[row] = (unsigned char)kp;
        above += kp;
    }
    #pragma unroll
    for (int w = 1; w < 64; w <<= 1) above += __shfl_xor(above, w, 64);
    if (lane == 0) aW[wid] = above;
    for (int i = tid; i < nb; i += 256) {
        int r = band[bh * BAND_CAP + i];
        bRow[i] = r;
        bM[i] = Mv[(size_t)bh * N + r];
    }
    __syncthreads();
    const int nAbove = aW[0] + aW[1] + aW[2] + aW[3];

    for (int i = tid; i < nb; i += 256) {
        const float mi = bM[i];
        const int ri = bRow[i];
        int rank = nAbove;
        for (int j = 0; j < nb; ++j) {
            float mj = bM[j];
            rank += (mj > mi) || (mj == mi && bRow[j] < ri);
        }
        int kp = (rank < NTOP) ? 1 : 0;
        kL[ri] = (unsigned char)kp;
        keep[(size_t)bh * N + ri] = kp;
    }
    __syncthreads();

    int cntL = 0;
    #pragma unroll
    for (int r = 0; r < 8; ++r) cntL += kL[tid * 8 + r];
    scan[tid] = cntL;
    __syncthreads();
    for (int s = 1; s < 256; s <<= 1) {
        int v = (tid >= s) ? scan[tid - s] : 0;
        __syncthreads();
        scan[tid] += v;
        __syncthreads();
    }
    int pos = scan[tid] - cntL;
    #pragma unroll
    for (int r = 0; r < 8; ++r) {
        int row = tid * 8 + r;
        if (kL[row]) {
            kidx[bh * NTOP + pos] = row;
            inv[(size_t)bh * N + row] = pos;
            ++pos;
        }
    }
}

// ---------------------------------------------------------------------------
// MFMA attention, split-K x2 (r13-verified): unnormalized partials.
// ---------------------------------------------------------------------------
__global__ __launch_bounds__(256) void attn_mfma(
    const u16* __restrict__ qh_, const u16* __restrict__ ql_,
    const u16* __restrict__ kh_, const u16* __restrict__ kl_,
    const u16* __restrict__ vth_, const u16* __restrict__ vtl_,
    const float* __restrict__ rowmax, const int* __restrict__ kidx,
    float* __restrict__ part_o, float* __restrict__ part_l)
{
    __shared__ __align__(16) u16 Kh[64 * 64], Kl[64 * 64];
    __shared__ __align__(16) u16 Vh[64 * 64], Vl[64 * 64];
    __shared__ __align__(16) u16 Ph[4][16 * 64], Pl[4][16 * 64];

    const int tid = threadIdx.x, lane = tid & 63, wave = tid >> 6;
    const int wg = blockIdx.x & 255;
    const int half = blockIdx.x >> 8;
    const int ks0 = half * (N / 2);
    const int bh = ((wg >> 6) << 3) | (wg & 7);
    const int xblk = (wg >> 3) & 7;
    const int q0 = xblk * 64 + wave * 16;
    const int fr = lane & 15, sl = lane >> 4;

    const bool isV = (wave >= 2);
    const u16* ksrc = (wave & 1) ? kl_ : kh_;
    const u16* vsrc = (wave & 1) ? vtl_ : vth_;
    u16* lbase = (wave == 0) ? Kh : (wave == 1) ? Kl : (wave == 2) ? Vh : Vl;
    const size_t kbase0 = (size_t)bh * N * DK;
    const size_t vbase0 = (size_t)bh * DK * N;

    const int* kix = kidx + bh * NTOP;
    const int qrow_f = kix[q0 + fr];
    float rmax_r[4];
    #pragma unroll
    for (int r = 0; r < 4; ++r)
        rmax_r[r] = rowmax[(size_t)bh * N + kix[q0 + sl * 4 + r]];

    short8v qfh[2], qfl[2];
    #pragma unroll
    for (int kk = 0; kk < 2; ++kk) {
        size_t qa = ((size_t)bh * N + qrow_f) * DK + kk * 32 + sl * 8;
        qfh[kk] = *(const short8v*)&qh_[qa];
        qfl[kk] = *(const short8v*)&ql_[qa];
    }

    f32x4 opv[4] = {};
    float lsum[4] = {};

    for (int kt = ks0; kt < ks0 + N / 2; kt += 64) {
        __syncthreads();
        #pragma unroll
        for (int i = 0; i < 8; ++i) {
            int c = i * 64 + lane;
            int row = c >> 3, sp = c & 7;
            int gs = sp ^ (row & 7);
            const u16* g = isV ? (vsrc + vbase0 + (size_t)row * N + kt + gs * 8)
                               : (ksrc + kbase0 + (size_t)(kt + row) * DK + gs * 8);
            gload16(g, lbase + (size_t)i * 512);
        }
        __syncthreads();

        #pragma unroll
        for (int n = 0; n < 4; ++n) {
            f32x4 a = {};
            __builtin_amdgcn_s_setprio(1);
            #pragma unroll
            for (int kk = 0; kk < 2; ++kk) {
                int key = n * 16 + fr;
                int off = key * 64 + (((sl + kk * 4) ^ (key & 7)) * 8);
                short8v bh_f = *(const short8v*)&Kh[off];
                short8v bl_f = *(const short8v*)&Kl[off];
                a = __builtin_amdgcn_mfma_f32_16x16x32_bf16(qfl[kk], bh_f, a, 0, 0, 0);
                a = __builtin_amdgcn_mfma_f32_16x16x32_bf16(qfh[kk], bl_f, a, 0, 0, 0);
                a = __builtin_amdgcn_mfma_f32_16x16x32_bf16(qfh[kk], bh_f, a, 0, 0, 0);
            }
            __builtin_amdgcn_s_setprio(0);
            #pragma unroll
            for (int r = 0; r < 4; ++r) {
                float p = __expf(a[r] * SCALE - rmax_r[r]);
                lsum[r] += p;
                u16 ph = bf16_rne(p);
                u16 pl = bf16_rne(p - __uint_as_float((unsigned)ph << 16));
                int q_l = sl * 4 + r;
                int key = n * 16 + fr;
                int off = q_l * 64 + (((key >> 3) ^ (q_l & 7)) * 8) + (key & 7);
                Ph[wave][off] = ph;
                Pl[wave][off] = pl;
            }
        }

        __builtin_amdgcn_s_setprio(1);
        #pragma unroll
        for (int kk = 0; kk < 2; ++kk) {
            int aoff = fr * 64 + (((kk * 4 + sl) ^ (fr & 7)) * 8);
            short8v pah = *(const short8v*)&Ph[wave][aoff];
            short8v pal = *(const short8v*)&Pl[wave][aoff];
            #pragma unroll
            for (int n = 0; n < 4; ++n) {
                int d = n * 16 + fr;
                int voff = d * 64 + (((kk * 4 + sl) ^ (d & 7)) * 8);
                short8v vhf = *(const short8v*)&Vh[voff];
                short8v vlf = *(const short8v*)&Vl[voff];
                opv[n] = __builtin_amdgcn_mfma_f32_16x16x32_bf16(pal, vhf, opv[n], 0, 0, 0);
                opv[n] = __builtin_amdgcn_mfma_f32_16x16x32_bf16(pah, vlf, opv[n], 0, 0, 0);
                opv[n] = __builtin_amdgcn_mfma_f32_16x16x32_bf16(pah, vhf, opv[n], 0, 0, 0);
            }
        }
        __builtin_amdgcn_s_setprio(0);
    }

    #pragma unroll
    for (int w = 1; w < 16; w <<= 1)
        #pragma unroll
        for (int r = 0; r < 4; ++r)
            lsum[r] += __shfl_xor(lsum[r], w, 64);

    const size_t pbase = ((size_t)half * BH + bh) * NTOP;
    #pragma unroll
    for (int r = 0; r < 4; ++r) {
        const int pos = q0 + sl * 4 + r;
        if (fr == 0) part_l[pbase + pos] = lsum[r];
        #pragma unroll
        for (int n = 0; n < 4; ++n)
            part_o[(pbase + pos) * DK + n * 16 + fr] = opv[n][r];
    }
}

// ---------------------------------------------------------------------------
// Epilogue: kept -> (o1+o2)/(l1+l2), non-kept -> vmean (from partials);
// writes bf16 hi/lo of attn_out directly (feeds gemm<1>). grid (16, B*H).
// ---------------------------------------------------------------------------
__global__ __launch_bounds__(256) void attn_epilogue(
    const float* __restrict__ part_o, const float* __restrict__ part_l,
    const int* __restrict__ keep, const int* __restrict__ inv,
    const float* __restrict__ partial,
    u16* __restrict__ aohi, u16* __restrict__ aolo)
{
    __shared__ float vm[DK];
    const int bh = blockIdx.y;
    const int b = bh >> 4, h = bh & 15;
    const int r0 = blockIdx.x * 128;
    const int tid = threadIdx.x;

    if (tid < DK) {
        const float* p = partial + ((size_t)0 * BH + bh) * CSEG * DK;
        float s = 0.f;
        #pragma unroll
        for (int g = 0; g < CSEG; ++g) s += p[g * DK + tid];
        vm[tid] = s / (float)N;
    }
    __syncthreads();

    #pragma unroll
    for (int it = 0; it < 8; ++it) {
        const int idx4 = it * 256 + tid;       // 0..2047 float4s
        const int row = r0 + (idx4 >> 4);
        const int d0 = (idx4 & 15) * 4;
        float o[4];
        if (keep[(size_t)bh * N + row]) {
            const int pos = inv[(size_t)bh * N + row];
            const size_t p0 = ((size_t)0 * BH + bh) * NTOP + pos;
            const size_t p1 = ((size_t)1 * BH + bh) * NTOP + pos;
            const float l = part_l[p0] + part_l[p1];
            const float4 a = *(const float4*)&part_o[p0 * DK + d0];
            const float4 c = *(const float4*)&part_o[p1 * DK + d0];
            o[0] = (a.x + c.x) / l; o[1] = (a.y + c.y) / l;
            o[2] = (a.z + c.z) / l; o[3] = (a.w + c.w) / l;
        } else {
            o[0] = vm[d0]; o[1] = vm[d0 + 1]; o[2] = vm[d0 + 2]; o[3] = vm[d0 + 3];
        }
        ushort4 hh, ll;
        u16* hp = (u16*)&hh; u16* lp = (u16*)&ll;
        #pragma unroll
        for (int j = 0; j < 4; ++j) {
            u16 hv = bf16_rne(o[j]);
            hp[j] = hv;
            lp[j] = bf16_rne(o[j] - __uint_as_float((unsigned)hv << 16));
        }
        const size_t oa = ((size_t)b * N + row) * C + h * DK + d0;
        *(ushort4*)&aohi[oa] = hh;
        *(ushort4*)&aolo[oa] = ll;
    }
}

// ---------------------------------------------------------------------------
extern "C" void kernel_launch(void* const* d_in, const int* in_sizes, int n_in,
                              void* d_out, int out_size, void* d_ws, size_t ws_size,
                              hipStream_t stream)
{
    const float* x    = (const float*)d_in[0];
    const float* Wqkv = (const float*)d_in[1];
    const float* bqkv = (const float*)d_in[2];
    const float* Wout = (const float*)d_in[3];
    const float* bout = (const float*)d_in[4];
    float* out = (float*)d_out;

    char* ws = (char*)d_ws;
    size_t off = 0;
    auto alloc = [&](size_t bytes) -> void* {
        void* p = ws + off;
        off += (bytes + 255) & ~(size_t)255;
        return p;
    };

    const size_t BHND = (size_t)B * H * N * DK;       // 4 Mi elems
    float* q        = (float*)alloc(BHND * 4);
    float* kbuf     = (float*)alloc(BHND * 4);
    float* vbuf     = (float*)alloc(BHND * 4);
    u16* cvAhi = (u16*)alloc((size_t)B * N * C * 2);  // x hi/lo
    u16* cvAlo = (u16*)alloc((size_t)B * N * C * 2);
    u16* cvBhi = (u16*)alloc((size_t)3 * C * C * 2);  // Wqkv hi/lo
    u16* cvBlo = (u16*)alloc((size_t)3 * C * C * 2);
    u16* cvWohi = (u16*)alloc((size_t)C * C * 2);     // Wout hi/lo
    u16* cvWolo = (u16*)alloc((size_t)C * C * 2);
    u16* aohi  = (u16*)alloc((size_t)B * N * C * 2);  // attn_out hi/lo
    u16* aolo  = (u16*)alloc((size_t)B * N * C * 2);
    u16* qhi   = (u16*)alloc(BHND * 2);
    u16* qlo   = (u16*)alloc(BHND * 2);
    u16* khi   = (u16*)alloc(BHND * 2);
    u16* klo   = (u16*)alloc(BHND * 2);
    u16* vthi  = (u16*)alloc(BHND * 2);
    u16* vtlo  = (u16*)alloc(BHND * 2);
    float* Mbuf     = (float*)alloc((size_t)BH * N * 4);
    float* rmaxbuf  = (float*)alloc((size_t)BH * N * 4);
    float* Mdot     = (float*)alloc((size_t)BH * N * 4);
    int*   keep     = (int*)  alloc((size_t)BH * N * 4);
    int*   inv      = (int*)  alloc((size_t)BH * N * 4);
    int*   kidx     = (int*)  alloc((size_t)BH * NTOP * 4);
    float* partbuf  = (float*)alloc((size_t)2 * BH * CSEG * DK * 4);
    float* thrbuf   = (float*)alloc((size_t)BH * 4);
    int*   cntbuf   = (int*)  alloc((size_t)BH * 4);
    int*   bandbuf  = (int*)  alloc((size_t)BH * BAND_CAP * 4);
    float* part_o   = (float*)alloc((size_t)2 * BH * NTOP * DK * 4);  // 8 MB
    float* part_l   = (float*)alloc((size_t)2 * BH * NTOP * 4);

    const int nX = B * N * C;        // 4M

    // 1. convert x, Wqkv, Wout to bf16 hi/lo (one launch, 8192 blocks)
    convert_hilo3<<<8192, 256, 0, stream>>>(
        x, Wqkv, Wout, cvAhi, cvAlo, cvBhi, cvBlo, cvWohi, cvWolo);

    // 2. QKV projection (2D grid — r9/r12-verified config)
    gemm_mfma<0><<<dim3(3 * C / 128, (B * N) / 128), 256, 0, stream>>>(
        cvAhi, cvAlo, cvBhi, cvBlo, bqkv, nullptr, q, kbuf, vbuf, C);

    // 3. convert q,k hi/lo (one launch); v transposed hi/lo
    convert_hilo2<<<dim3(nX / 1024, 2), 256, 0, stream>>>(
        q, kbuf, qhi, qlo, khi, klo, nX);
    convert_hilo_T<<<dim3(N / 64, BH), 256, 0, stream>>>(vbuf, vthi, vtlo);

    // 4. column sums of v and k (partials only; finals reduced in consumers)
    colsum_part2<<<dim3(CSEG, BH, 2), 256, 0, stream>>>(vbuf, kbuf, partbuf);

    // 5. mean term per row: Mdot = q . kmean (kmean reduced in-block)
    qdot_kernel<<<dim3(N / 256, BH), 256, 0, stream>>>(q, partbuf, Mdot);

    // 6. MFMA approximate row max -> M, rowmax (2D grid)
    row_stats_mfma<<<dim3(N / 128, BH), 256, 0, stream>>>(
        qhi, qlo, khi, klo, Mdot, Mbuf, rmaxbuf);

    // 7. selection: thr (+cnt init) -> classify -> fp64 refine -> finalize(+inv)
    topk_thr<<<dim3(N / 256, BH), 256, 0, stream>>>(Mbuf, thrbuf, cntbuf);
    band_classify<<<dim3(N / 256, BH), 256, 0, stream>>>(Mbuf, thrbuf, cntbuf, bandbuf, keep);
    refine_kernel<<<dim3(32, BH), 256, 0, stream>>>(q, kbuf, cntbuf, bandbuf, Mbuf);
    band_finalize<<<BH, 256, 0, stream>>>(Mbuf, cntbuf, bandbuf, keep, kidx, inv);

    // 8. split-K MFMA attention (partials) + fused epilogue (merge + vmean +
    //    direct bf16 hi/lo output)
    attn_mfma<<<512, 256, 0, stream>>>(
        qhi, qlo, khi, klo, vthi, vtlo, rmaxbuf, kidx, part_o, part_l);
    attn_epilogue<<<dim3(16, BH), 256, 0, stream>>>(
        part_o, part_l, keep, inv, partbuf, aohi, aolo);

    // 9. Output projection (2D grid) — consumes epilogue's hi/lo directly
    gemm_mfma<1><<<dim3(C / 128, (B * N) / 128), 256, 0, stream>>>(
        aohi, aolo, cvWohi, cvWolo, bout, out, nullptr, nullptr, nullptr, C);
}

// Round 15
// 368.767 us; speedup vs baseline: 1.3168x; 1.0132x over previous
//
#include <hip/hip_runtime.h>
#include <math.h>

typedef unsigned short u16;
typedef __attribute__((ext_vector_type(8))) short short8v;  // 8 bf16 operand frag
typedef __attribute__((ext_vector_type(4))) float f32x4;    // MFMA accumulator

constexpr int B  = 2;
constexpr int N  = 2048;
constexpr int C  = 1024;
constexpr int H  = 16;
constexpr int BH = B * H;
constexpr int DK = 64;
constexpr int NTOP = 512;
constexpr float SCALE = 0.125f;  // 1/sqrt(64)
constexpr int   BAND_CAP = 1024;
constexpr float BAND_EPS = 2e-3f;   // covers 3-term split-bf16 M error (~1e-4)
constexpr int   CSEG = 16;          // column-sum segments per bh

// ---------------------------------------------------------------------------
// async global -> LDS, 16B per lane. (verified r8)
// ---------------------------------------------------------------------------
__device__ __forceinline__ void gload16(const u16* g, u16* l) {
    __builtin_amdgcn_global_load_lds(
        (const __attribute__((address_space(1))) unsigned int*)g,
        (__attribute__((address_space(3))) unsigned int*)l,
        16, 0, 0);
}

// ---------------------------------------------------------------------------
// fp32 -> bf16 hi/lo split (RNE)
// ---------------------------------------------------------------------------
__device__ __forceinline__ u16 bf16_rne(float x) {
    unsigned u = __float_as_uint(x);
    unsigned r = u + 0x7fffu + ((u >> 16) & 1u);
    return (u16)(r >> 16);
}

// one launch converts x (4096 blk), Wqkv (3072 blk), Wout (1024 blk)
__global__ __launch_bounds__(256) void convert_hilo3(
    const float* __restrict__ x, const float* __restrict__ wqkv,
    const float* __restrict__ wout,
    u16* __restrict__ xh, u16* __restrict__ xl,
    u16* __restrict__ wh, u16* __restrict__ wl,
    u16* __restrict__ woh, u16* __restrict__ wol)
{
    const int bid = blockIdx.x;
    const float* src; u16* hi; u16* lo; int base;
    if (bid < 4096)      { src = x;    hi = xh;  lo = xl;  base = bid; }
    else if (bid < 7168) { src = wqkv; hi = wh;  lo = wl;  base = bid - 4096; }
    else                 { src = wout; hi = woh; lo = wol; base = bid - 7168; }
    int i = (base * 256 + threadIdx.x) * 4;
    float4 v = *(const float4*)&src[i];
    u16 h0 = bf16_rne(v.x), h1 = bf16_rne(v.y), h2 = bf16_rne(v.z), h3 = bf16_rne(v.w);
    float f0 = __uint_as_float((unsigned)h0 << 16);
    float f1 = __uint_as_float((unsigned)h1 << 16);
    float f2 = __uint_as_float((unsigned)h2 << 16);
    float f3 = __uint_as_float((unsigned)h3 << 16);
    *(ushort4*)&hi[i] = make_ushort4(h0, h1, h2, h3);
    *(ushort4*)&lo[i] = make_ushort4(bf16_rne(v.x - f0), bf16_rne(v.y - f1),
                                     bf16_rne(v.z - f2), bf16_rne(v.w - f3));
}

// two-source variant (q and k in one launch); grid (n/1024, 2)
__global__ __launch_bounds__(256) void convert_hilo2(
    const float* __restrict__ a, const float* __restrict__ b,
    u16* __restrict__ ah, u16* __restrict__ al,
    u16* __restrict__ bh_, u16* __restrict__ bl_, int n)
{
    const float* src = blockIdx.y ? b : a;
    u16* hi = blockIdx.y ? bh_ : ah;
    u16* lo = blockIdx.y ? bl_ : al;
    int i = (blockIdx.x * 256 + threadIdx.x) * 4;
    if (i >= n) return;
    float4 v = *(const float4*)&src[i];
    u16 h0 = bf16_rne(v.x), h1 = bf16_rne(v.y), h2 = bf16_rne(v.z), h3 = bf16_rne(v.w);
    float f0 = __uint_as_float((unsigned)h0 << 16);
    float f1 = __uint_as_float((unsigned)h1 << 16);
    float f2 = __uint_as_float((unsigned)h2 << 16);
    float f3 = __uint_as_float((unsigned)h3 << 16);
    *(ushort4*)&hi[i] = make_ushort4(h0, h1, h2, h3);
    *(ushort4*)&lo[i] = make_ushort4(bf16_rne(v.x - f0), bf16_rne(v.y - f1),
                                     bf16_rne(v.z - f2), bf16_rne(v.w - f3));
}

// ---------------------------------------------------------------------------
// Transposed convert: v (bh, key, d) fp32 -> vt hi/lo (bh, d, key) bf16. (r6)
// ---------------------------------------------------------------------------
__global__ __launch_bounds__(256) void convert_hilo_T(
    const float* __restrict__ v, u16* __restrict__ th, u16* __restrict__ tl)
{
    constexpr int LS = 68;
    __shared__ u16 Sh[64 * LS], Sl[64 * LS];
    const int bh = blockIdx.y;
    const int kt = blockIdx.x * 64;
    const int tid = threadIdx.x;
    #pragma unroll
    for (int p = 0; p < 4; ++p) {
        int idx = tid * 4 + p * 1024;
        int key = idx >> 6, d = idx & 63;
        float4 x4 = *(const float4*)&v[((size_t)bh * N + kt + key) * DK + d];
        float xs[4] = {x4.x, x4.y, x4.z, x4.w};
        ushort4 hh, ll;
        u16* hp = (u16*)&hh; u16* lp = (u16*)&ll;
        #pragma unroll
        for (int j = 0; j < 4; ++j) {
            u16 h = bf16_rne(xs[j]);
            hp[j] = h;
            lp[j] = bf16_rne(xs[j] - __uint_as_float((unsigned)h << 16));
        }
        *(ushort4*)&Sh[key * LS + d] = hh;
        *(ushort4*)&Sl[key * LS + d] = ll;
    }
    __syncthreads();
    const int d = tid >> 2, seg = tid & 3;
    u16 bufh[16], bufl[16];
    #pragma unroll
    for (int i = 0; i < 16; ++i) {
        bufh[i] = Sh[(seg * 16 + i) * LS + d];
        bufl[i] = Sl[(seg * 16 + i) * LS + d];
    }
    size_t oa = ((size_t)bh * DK + d) * N + kt + seg * 16;
    *(uint4*)&th[oa] = ((uint4*)bufh)[0];
    *(uint4*)&th[oa + 8] = ((uint4*)bufh)[1];
    *(uint4*)&tl[oa] = ((uint4*)bufl)[0];
    *(uint4*)&tl[oa + 8] = ((uint4*)bufl)[1];
}

// ---------------------------------------------------------------------------
// Split-bf16 MFMA GEMM: 128x128 tile, BK=32, 4 waves, gload staging.
// 2D grid (r9/r12-verified config).
// ---------------------------------------------------------------------------
template <int MODE>
__global__ __launch_bounds__(256) void gemm_mfma(
    const u16* __restrict__ Ahi, const u16* __restrict__ Alo,
    const u16* __restrict__ Bhi, const u16* __restrict__ Blo,
    const float* __restrict__ bias, float* __restrict__ out,
    float* __restrict__ qb, float* __restrict__ kb, float* __restrict__ vb,
    int K)
{
    __shared__ __align__(16) u16 Ah[128 * 32], Al[128 * 32];
    __shared__ __align__(16) u16 Bh[128 * 32], Bl[128 * 32];

    const int tid = threadIdx.x;
    const int m0 = blockIdx.y * 128;
    const int n0 = blockIdx.x * 128;
    const int lane = tid & 63;
    const int wave = tid >> 6;
    const int wr = wave >> 1, wc = wave & 1;
    const int fr = lane & 15, sl = lane >> 4;

    const u16* gsrc = (wave == 0) ? Ahi + (size_t)m0 * K
                    : (wave == 1) ? Alo + (size_t)m0 * K
                    : (wave == 2) ? Bhi + (size_t)n0 * K
                                  : Blo + (size_t)n0 * K;
    u16* lbase = (wave == 0) ? Ah : (wave == 1) ? Al : (wave == 2) ? Bh : Bl;

    f32x4 acc[4][4] = {};

    for (int k0 = 0; k0 < K; k0 += 32) {
        __syncthreads();
        #pragma unroll
        for (int i = 0; i < 8; ++i) {
            int c = i * 64 + lane;               // chunk = 16B = 8 u16
            int row = c >> 2, sp = c & 3;
            int gs = sp ^ ((row >> 1) & 3);
            gload16(gsrc + (size_t)row * K + k0 + gs * 8, lbase + i * 512);
        }
        __syncthreads();

        short8v afh[4], afl[4], bfh[4], bfl[4];
        #pragma unroll
        for (int m = 0; m < 4; ++m) {
            int row = wr * 64 + m * 16 + fr;
            int off = row * 32 + ((sl ^ ((row >> 1) & 3)) * 8);
            afh[m] = *(const short8v*)&Ah[off];
            afl[m] = *(const short8v*)&Al[off];
        }
        #pragma unroll
        for (int n = 0; n < 4; ++n) {
            int row = wc * 64 + n * 16 + fr;
            int off = row * 32 + ((sl ^ ((row >> 1) & 3)) * 8);
            bfh[n] = *(const short8v*)&Bh[off];
            bfl[n] = *(const short8v*)&Bl[off];
        }
        #pragma unroll
        for (int m = 0; m < 4; ++m)
            #pragma unroll
            for (int n = 0; n < 4; ++n) {
                acc[m][n] = __builtin_amdgcn_mfma_f32_16x16x32_bf16(afh[m], bfh[n], acc[m][n], 0, 0, 0);
                acc[m][n] = __builtin_amdgcn_mfma_f32_16x16x32_bf16(afh[m], bfl[n], acc[m][n], 0, 0, 0);
                acc[m][n] = __builtin_amdgcn_mfma_f32_16x16x32_bf16(afl[m], bfh[n], acc[m][n], 0, 0, 0);
            }
    }

    #pragma unroll
    for (int m = 0; m < 4; ++m)
        #pragma unroll
        for (int n = 0; n < 4; ++n)
            #pragma unroll
            for (int r = 0; r < 4; ++r) {
                int grow = m0 + wr * 64 + m * 16 + sl * 4 + r;
                int gcol = n0 + wc * 64 + n * 16 + fr;
                float val = acc[m][n][r] + bias[gcol];
                if (MODE == 0) {
                    int t = gcol >> 10, h = (gcol >> 6) & 15, d = gcol & 63;
                    int bb = grow >> 11, nn = grow & (N - 1);
                    float* dst = (t == 0) ? qb : (t == 1) ? kb : vb;
                    dst[(((size_t)bb * H + h) * N + nn) * DK + d] = val;
                } else {
                    out[(size_t)grow * C + gcol] = val;
                }
            }
}

// ---------------------------------------------------------------------------
// Column sums over v and k in one launch.  grid (CSEG, B*H, 2), z: 0=v 1=k.
// ---------------------------------------------------------------------------
__global__ __launch_bounds__(256) void colsum_part2(
    const float* __restrict__ v, const float* __restrict__ k,
    float* __restrict__ partial)
{
    const int bh = blockIdx.y, seg = blockIdx.x, which = blockIdx.z;
    const float* src = which ? k : v;
    const int d = threadIdx.x & 63;
    const int sub = threadIdx.x >> 6;
    const int k0 = seg * (N / CSEG);
    float s = 0.f;
    for (int kk = sub; kk < N / CSEG; kk += 4)
        s += src[((size_t)bh * N + k0 + kk) * DK + d];
    __shared__ float part[4][64];
    part[sub][d] = s;
    __syncthreads();
    if (threadIdx.x < 64)
        partial[(((size_t)which * BH + bh) * CSEG + seg) * DK + d] =
            part[0][d] + part[1][d] + part[2][d] + part[3][d];
}

// ---------------------------------------------------------------------------
// Mdot[bh,row] = dot(q_row, kmean_bh); kmean reduced from partials in-block.
// ---------------------------------------------------------------------------
__global__ __launch_bounds__(256) void qdot_kernel(
    const float* __restrict__ q, const float* __restrict__ partial,
    float* __restrict__ Mdot)
{
    const int bh = blockIdx.y;
    const int row = blockIdx.x * 256 + threadIdx.x;
    __shared__ float km[DK];
    if (threadIdx.x < DK) {
        const float* p = partial + ((size_t)1 * BH + bh) * CSEG * DK;
        float s = 0.f;
        #pragma unroll
        for (int g = 0; g < CSEG; ++g) s += p[g * DK + threadIdx.x];
        km[threadIdx.x] = s / (float)N;
    }
    __syncthreads();
    const float* qr = &q[((size_t)bh * N + row) * DK];
    float s = 0.f;
    #pragma unroll
    for (int d4 = 0; d4 < DK; d4 += 4) {
        float4 v = *(const float4*)&qr[d4];
        s += v.x * km[d4] + v.y * km[d4 + 1] + v.z * km[d4 + 2] + v.w * km[d4 + 3];
    }
    Mdot[(size_t)bh * N + row] = s;
}

// ---------------------------------------------------------------------------
// MFMA row-max (3-term), gload staging. 2D grid (r9/r12-verified).
// ---------------------------------------------------------------------------
__global__ __launch_bounds__(256) void row_stats_mfma(
    const u16* __restrict__ qh_, const u16* __restrict__ ql_,
    const u16* __restrict__ kh_, const u16* __restrict__ kl_,
    const float* __restrict__ Mdot, float* __restrict__ Mout,
    float* __restrict__ rowmax)
{
    __shared__ __align__(16) u16 Kh[64 * 64];
    __shared__ __align__(16) u16 Kl[64 * 64];
    const int tid = threadIdx.x, lane = tid & 63, wave = tid >> 6;
    const int bh = blockIdx.y;
    const int q0 = blockIdx.x * 128 + wave * 32;
    const int fr = lane & 15, g = lane >> 4;

    const u16* gsrc = (wave & 2) ? kl_ : kh_;
    u16* lbase = (wave & 2) ? Kl : Kh;
    const int cb = (wave & 1) * 256;

    short8v qfh[2][2], qfl[2][2];
    #pragma unroll
    for (int m = 0; m < 2; ++m)
        #pragma unroll
        for (int kk = 0; kk < 2; ++kk) {
            size_t qa = ((size_t)bh * N + q0 + m * 16 + fr) * DK + kk * 32 + g * 8;
            qfh[m][kk] = *(const short8v*)&qh_[qa];
            qfl[m][kk] = *(const short8v*)&ql_[qa];
        }

    f32x4 mx[2];
    mx[0] = (f32x4){-1e30f, -1e30f, -1e30f, -1e30f};
    mx[1] = mx[0];

    for (int kt = 0; kt < N; kt += 64) {
        __syncthreads();
        #pragma unroll
        for (int i = 0; i < 4; ++i) {
            int c = cb + i * 64 + lane;
            int row = c >> 3, sp = c & 7;
            int gs = sp ^ (row & 7);
            gload16(gsrc + ((size_t)bh * N + kt + row) * DK + gs * 8,
                    lbase + (size_t)(cb + i * 64) * 8);
        }
        __syncthreads();
        short8v bfh[4][2], bfl[4][2];
        #pragma unroll
        for (int n = 0; n < 4; ++n)
            #pragma unroll
            for (int kk = 0; kk < 2; ++kk) {
                int key = n * 16 + fr;
                int off = key * 64 + (((g + kk * 4) ^ (key & 7)) * 8);
                bfh[n][kk] = *(const short8v*)&Kh[off];
                bfl[n][kk] = *(const short8v*)&Kl[off];
            }
        #pragma unroll
        for (int m = 0; m < 2; ++m)
            #pragma unroll
            for (int n = 0; n < 4; ++n) {
                f32x4 a = {};
                #pragma unroll
                for (int kk = 0; kk < 2; ++kk) {
                    a = __builtin_amdgcn_mfma_f32_16x16x32_bf16(qfl[m][kk], bfh[n][kk], a, 0, 0, 0);
                    a = __builtin_amdgcn_mfma_f32_16x16x32_bf16(qfh[m][kk], bfl[n][kk], a, 0, 0, 0);
                    a = __builtin_amdgcn_mfma_f32_16x16x32_bf16(qfh[m][kk], bfh[n][kk], a, 0, 0, 0);
                }
                #pragma unroll
                for (int r = 0; r < 4; ++r) mx[m][r] = fmaxf(mx[m][r], a[r]);
            }
    }

    #pragma unroll
    for (int w = 1; w < 16; w <<= 1)
        #pragma unroll
        for (int m = 0; m < 2; ++m)
            #pragma unroll
            for (int r = 0; r < 4; ++r)
                mx[m][r] = fmaxf(mx[m][r], __shfl_xor(mx[m][r], w, 64));

    if (fr == 0) {
        #pragma unroll
        for (int m = 0; m < 2; ++m)
            #pragma unroll
            for (int r = 0; r < 4; ++r) {
                int row = q0 + m * 16 + g * 4 + r;
                size_t idx = (size_t)bh * N + row;
                float v = mx[m][r];
                rowmax[idx] = SCALE * v;
                Mout[idx]   = SCALE * (v - Mdot[idx]);
            }
    }
}

// ---------------------------------------------------------------------------
// Selection: thr (+cnt init) -> classify -> fp64 refine -> finalize (+inv).
// ---------------------------------------------------------------------------
__global__ __launch_bounds__(256) void topk_thr(
    const float* __restrict__ Mv, float* __restrict__ thr, int* __restrict__ cnt)
{
    const int bh = blockIdx.y;
    const int qi = blockIdx.x * 256 + threadIdx.x;
    if (blockIdx.x == 0 && threadIdx.x == 0) cnt[bh] = 0;
    __shared__ float Ms[N];
    for (int e = threadIdx.x; e < N; e += 256) Ms[e] = Mv[(size_t)bh * N + e];
    __syncthreads();
    const float mq = Ms[qi];
    int rank = 0;
    for (int j = 0; j < N; ++j) {
        float mj = Ms[j];
        rank += (mj > mq) || (mj == mq && j < qi);
    }
    if (rank == NTOP - 1) thr[bh] = mq;   // smallest kept (approx boundary)
}

__global__ __launch_bounds__(256) void band_classify(
    const float* __restrict__ Mv, const float* __restrict__ thr,
    int* __restrict__ cnt, int* __restrict__ band, int* __restrict__ keep)
{
    const int bh = blockIdx.y;
    const int row = blockIdx.x * 256 + threadIdx.x;
    const float m = Mv[(size_t)bh * N + row];
    const float t = thr[bh];
    int kp;
    if (fabsf(m - t) <= BAND_EPS) {
        int pos = atomicAdd(&cnt[bh], 1);
        if (pos < BAND_CAP) band[bh * BAND_CAP + pos] = row;
        kp = 0;
    } else {
        kp = (m > t) ? 1 : 0;
    }
    keep[(size_t)bh * N + row] = kp;
}

// Block-per-candidate (strided): LDS-staged coalesced K, fp64 exact dot.
// All 4 waves participate in the dot: wave w handles dims [16w,16w+16) of
// key=lane; per-tile cross-wave merge via LDS. 4x shorter fp64 dep chains
// than the r10 single-wave form (same math, fp64 tree-sum reassociation).
__global__ __launch_bounds__(256) void refine_kernel(
    const float* __restrict__ q, const float* __restrict__ k,
    const int* __restrict__ cnt, const int* __restrict__ band,
    float* __restrict__ Mv)
{
    constexpr int LS = 69;
    __shared__ float Ks[64 * LS];
    __shared__ float qs[DK];
    __shared__ double pp[4][64];
    const int bh = blockIdx.y;
    const int tid = threadIdx.x;
    const int wave = tid >> 6, lane = tid & 63;
    const int n = min(cnt[bh], BAND_CAP);
    for (int ci = blockIdx.x; ci < n; ci += 32) {
        const int row = band[bh * BAND_CAP + ci];
        __syncthreads();   // prev candidate done with qs/Ks/pp
        if (tid < DK) qs[tid] = q[((size_t)bh * N + row) * DK + tid];
        double mx = -1e30, sm = 0.0;   // meaningful in wave 0 only
        for (int kt = 0; kt < N; kt += 64) {
            __syncthreads();
            #pragma unroll
            for (int p = 0; p < 4; ++p) {
                int idx = tid * 4 + p * 1024;
                int kr = idx >> 6, d = idx & 63;
                float4 x4 = *(const float4*)&k[((size_t)bh * N + kt + kr) * DK + d];
                Ks[kr * LS + d]     = x4.x;
                Ks[kr * LS + d + 1] = x4.y;
                Ks[kr * LS + d + 2] = x4.z;
                Ks[kr * LS + d + 3] = x4.w;
            }
            __syncthreads();
            // partial dot: wave w, dims [16w, 16w+16), key = lane
            double s = 0.0;
            #pragma unroll
            for (int d = 0; d < 16; ++d)
                s += (double)qs[wave * 16 + d] *
                     (double)Ks[lane * LS + wave * 16 + d];
            pp[wave][lane] = s;
            __syncthreads();
            if (wave == 0) {
                double st = pp[0][lane] + pp[1][lane] + pp[2][lane] + pp[3][lane];
                mx = fmax(mx, st);
                sm += st;
            }
        }
        if (wave == 0) {
            #pragma unroll
            for (int w = 1; w < 64; w <<= 1) {
                mx = fmax(mx, __shfl_xor(mx, w, 64));
                sm += __shfl_xor(sm, w, 64);
            }
            if (lane == 0)
                Mv[(size_t)bh * N + row] = (float)((double)SCALE * (mx - sm / (double)N));
        }
    }
}

__global__ __launch_bounds__(256) void band_finalize(
    const float* __restrict__ Mv, const int* __restrict__ cnt,
    const int* __restrict__ band, int* __restrict__ keep,
    int* __restrict__ kidx, int* __restrict__ inv)
{
    __shared__ unsigned char kL[N];
    __shared__ int   bRow[BAND_CAP];
    __shared__ float bM[BAND_CAP];
    __shared__ int aW[4];
    __shared__ int scan[256];

    const int bh = blockIdx.x;
    const int tid = threadIdx.x;
    const int lane = tid & 63, wid = tid >> 6;
    const int nb = min(cnt[bh], BAND_CAP);

    int above = 0;
    #pragma unroll
    for (int w = 0; w < 8; ++w) {
        int row = w * 256 + tid;
        int kp = keep[(size_t)bh * N + row];
        kL[row] = (unsigned char)kp;
        above += kp;
    }
    #pragma unroll
    for (int w = 1; w < 64; w <<= 1) above += __shfl_xor(above, w, 64);
    if (lane == 0) aW[wid] = above;
    for (int i = tid; i < nb; i += 256) {
        int r = band[bh * BAND_CAP + i];
        bRow[i] = r;
        bM[i] = Mv[(size_t)bh * N + r];
    }
    __syncthreads();
    const int nAbove = aW[0] + aW[1] + aW[2] + aW[3];

    for (int i = tid; i < nb; i += 256) {
        const float mi = bM[i];
        const int ri = bRow[i];
        int rank = nAbove;
        for (int j = 0; j < nb; ++j) {
            float mj = bM[j];
            rank += (mj > mi) || (mj == mi && bRow[j] < ri);
        }
        int kp = (rank < NTOP) ? 1 : 0;
        kL[ri] = (unsigned char)kp;
        keep[(size_t)bh * N + ri] = kp;
    }
    __syncthreads();

    int cntL = 0;
    #pragma unroll
    for (int r = 0; r < 8; ++r) cntL += kL[tid * 8 + r];
    scan[tid] = cntL;
    __syncthreads();
    for (int s = 1; s < 256; s <<= 1) {
        int v = (tid >= s) ? scan[tid - s] : 0;
        __syncthreads();
        scan[tid] += v;
        __syncthreads();
    }
    int pos = scan[tid] - cntL;
    #pragma unroll
    for (int r = 0; r < 8; ++r) {
        int row = tid * 8 + r;
        if (kL[row]) {
            kidx[bh * NTOP + pos] = row;
            inv[(size_t)bh * N + row] = pos;
            ++pos;
        }
    }
}

// ---------------------------------------------------------------------------
// MFMA attention, split-K x2 (r13-verified): unnormalized partials.
// ---------------------------------------------------------------------------
__global__ __launch_bounds__(256) void attn_mfma(
    const u16* __restrict__ qh_, const u16* __restrict__ ql_,
    const u16* __restrict__ kh_, const u16* __restrict__ kl_,
    const u16* __restrict__ vth_, const u16* __restrict__ vtl_,
    const float* __restrict__ rowmax, const int* __restrict__ kidx,
    float* __restrict__ part_o, float* __restrict__ part_l)
{
    __shared__ __align__(16) u16 Kh[64 * 64], Kl[64 * 64];
    __shared__ __align__(16) u16 Vh[64 * 64], Vl[64 * 64];
    __shared__ __align__(16) u16 Ph[4][16 * 64], Pl[4][16 * 64];

    const int tid = threadIdx.x, lane = tid & 63, wave = tid >> 6;
    const int wg = blockIdx.x & 255;
    const int half = blockIdx.x >> 8;
    const int ks0 = half * (N / 2);
    const int bh = ((wg >> 6) << 3) | (wg & 7);
    const int xblk = (wg >> 3) & 7;
    const int q0 = xblk * 64 + wave * 16;
    const int fr = lane & 15, sl = lane >> 4;

    const bool isV = (wave >= 2);
    const u16* ksrc = (wave & 1) ? kl_ : kh_;
    const u16* vsrc = (wave & 1) ? vtl_ : vth_;
    u16* lbase = (wave == 0) ? Kh : (wave == 1) ? Kl : (wave == 2) ? Vh : Vl;
    const size_t kbase0 = (size_t)bh * N * DK;
    const size_t vbase0 = (size_t)bh * DK * N;

    const int* kix = kidx + bh * NTOP;
    const int qrow_f = kix[q0 + fr];
    float rmax_r[4];
    #pragma unroll
    for (int r = 0; r < 4; ++r)
        rmax_r[r] = rowmax[(size_t)bh * N + kix[q0 + sl * 4 + r]];

    short8v qfh[2], qfl[2];
    #pragma unroll
    for (int kk = 0; kk < 2; ++kk) {
        size_t qa = ((size_t)bh * N + qrow_f) * DK + kk * 32 + sl * 8;
        qfh[kk] = *(const short8v*)&qh_[qa];
        qfl[kk] = *(const short8v*)&ql_[qa];
    }

    f32x4 opv[4] = {};
    float lsum[4] = {};

    for (int kt = ks0; kt < ks0 + N / 2; kt += 64) {
        __syncthreads();
        #pragma unroll
        for (int i = 0; i < 8; ++i) {
            int c = i * 64 + lane;
            int row = c >> 3, sp = c & 7;
            int gs = sp ^ (row & 7);
            const u16* g = isV ? (vsrc + vbase0 + (size_t)row * N + kt + gs * 8)
                               : (ksrc + kbase0 + (size_t)(kt + row) * DK + gs * 8);
            gload16(g, lbase + (size_t)i * 512);
        }
        __syncthreads();

        #pragma unroll
        for (int n = 0; n < 4; ++n) {
            f32x4 a = {};
            __builtin_amdgcn_s_setprio(1);
            #pragma unroll
            for (int kk = 0; kk < 2; ++kk) {
                int key = n * 16 + fr;
                int off = key * 64 + (((sl + kk * 4) ^ (key & 7)) * 8);
                short8v bh_f = *(const short8v*)&Kh[off];
                short8v bl_f = *(const short8v*)&Kl[off];
                a = __builtin_amdgcn_mfma_f32_16x16x32_bf16(qfl[kk], bh_f, a, 0, 0, 0);
                a = __builtin_amdgcn_mfma_f32_16x16x32_bf16(qfh[kk], bl_f, a, 0, 0, 0);
                a = __builtin_amdgcn_mfma_f32_16x16x32_bf16(qfh[kk], bh_f, a, 0, 0, 0);
            }
            __builtin_amdgcn_s_setprio(0);
            #pragma unroll
            for (int r = 0; r < 4; ++r) {
                float p = __expf(a[r] * SCALE - rmax_r[r]);
                lsum[r] += p;
                u16 ph = bf16_rne(p);
                u16 pl = bf16_rne(p - __uint_as_float((unsigned)ph << 16));
                int q_l = sl * 4 + r;
                int key = n * 16 + fr;
                int off = q_l * 64 + (((key >> 3) ^ (q_l & 7)) * 8) + (key & 7);
                Ph[wave][off] = ph;
                Pl[wave][off] = pl;
            }
        }

        __builtin_amdgcn_s_setprio(1);
        #pragma unroll
        for (int kk = 0; kk < 2; ++kk) {
            int aoff = fr * 64 + (((kk * 4 + sl) ^ (fr & 7)) * 8);
            short8v pah = *(const short8v*)&Ph[wave][aoff];
            short8v pal = *(const short8v*)&Pl[wave][aoff];
            #pragma unroll
            for (int n = 0; n < 4; ++n) {
                int d = n * 16 + fr;
                int voff = d * 64 + (((kk * 4 + sl) ^ (d & 7)) * 8);
                short8v vhf = *(const short8v*)&Vh[voff];
                short8v vlf = *(const short8v*)&Vl[voff];
                opv[n] = __builtin_amdgcn_mfma_f32_16x16x32_bf16(pal, vhf, opv[n], 0, 0, 0);
                opv[n] = __builtin_amdgcn_mfma_f32_16x16x32_bf16(pah, vlf, opv[n], 0, 0, 0);
                opv[n] = __builtin_amdgcn_mfma_f32_16x16x32_bf16(pah, vhf, opv[n], 0, 0, 0);
            }
        }
        __builtin_amdgcn_s_setprio(0);
    }

    #pragma unroll
    for (int w = 1; w < 16; w <<= 1)
        #pragma unroll
        for (int r = 0; r < 4; ++r)
            lsum[r] += __shfl_xor(lsum[r], w, 64);

    const size_t pbase = ((size_t)half * BH + bh) * NTOP;
    #pragma unroll
    for (int r = 0; r < 4; ++r) {
        const int pos = q0 + sl * 4 + r;
        if (fr == 0) part_l[pbase + pos] = lsum[r];
        #pragma unroll
        for (int n = 0; n < 4; ++n)
            part_o[(pbase + pos) * DK + n * 16 + fr] = opv[n][r];
    }
}

// ---------------------------------------------------------------------------
// Epilogue: kept -> (o1+o2)/(l1+l2), non-kept -> vmean (from partials);
// writes bf16 hi/lo of attn_out directly (feeds gemm<1>). grid (16, B*H).
// ---------------------------------------------------------------------------
__global__ __launch_bounds__(256) void attn_epilogue(
    const float* __restrict__ part_o, const float* __restrict__ part_l,
    const int* __restrict__ keep, const int* __restrict__ inv,
    const float* __restrict__ partial,
    u16* __restrict__ aohi, u16* __restrict__ aolo)
{
    __shared__ float vm[DK];
    const int bh = blockIdx.y;
    const int b = bh >> 4, h = bh & 15;
    const int r0 = blockIdx.x * 128;
    const int tid = threadIdx.x;

    if (tid < DK) {
        const float* p = partial + ((size_t)0 * BH + bh) * CSEG * DK;
        float s = 0.f;
        #pragma unroll
        for (int g = 0; g < CSEG; ++g) s += p[g * DK + tid];
        vm[tid] = s / (float)N;
    }
    __syncthreads();

    #pragma unroll
    for (int it = 0; it < 8; ++it) {
        const int idx4 = it * 256 + tid;       // 0..2047 float4s
        const int row = r0 + (idx4 >> 4);
        const int d0 = (idx4 & 15) * 4;
        float o[4];
        if (keep[(size_t)bh * N + row]) {
            const int pos = inv[(size_t)bh * N + row];
            const size_t p0 = ((size_t)0 * BH + bh) * NTOP + pos;
            const size_t p1 = ((size_t)1 * BH + bh) * NTOP + pos;
            const float l = part_l[p0] + part_l[p1];
            const float4 a = *(const float4*)&part_o[p0 * DK + d0];
            const float4 c = *(const float4*)&part_o[p1 * DK + d0];
            o[0] = (a.x + c.x) / l; o[1] = (a.y + c.y) / l;
            o[2] = (a.z + c.z) / l; o[3] = (a.w + c.w) / l;
        } else {
            o[0] = vm[d0]; o[1] = vm[d0 + 1]; o[2] = vm[d0 + 2]; o[3] = vm[d0 + 3];
        }
        ushort4 hh, ll;
        u16* hp = (u16*)&hh; u16* lp = (u16*)&ll;
        #pragma unroll
        for (int j = 0; j < 4; ++j) {
            u16 hv = bf16_rne(o[j]);
            hp[j] = hv;
            lp[j] = bf16_rne(o[j] - __uint_as_float((unsigned)hv << 16));
        }
        const size_t oa = ((size_t)b * N + row) * C + h * DK + d0;
        *(ushort4*)&aohi[oa] = hh;
        *(ushort4*)&aolo[oa] = ll;
    }
}

// ---------------------------------------------------------------------------
extern "C" void kernel_launch(void* const* d_in, const int* in_sizes, int n_in,
                              void* d_out, int out_size, void* d_ws, size_t ws_size,
                              hipStream_t stream)
{
    const float* x    = (const float*)d_in[0];
    const float* Wqkv = (const float*)d_in[1];
    const float* bqkv = (const float*)d_in[2];
    const float* Wout = (const float*)d_in[3];
    const float* bout = (const float*)d_in[4];
    float* out = (float*)d_out;

    char* ws = (char*)d_ws;
    size_t off = 0;
    auto alloc = [&](size_t bytes) -> void* {
        void* p = ws + off;
        off += (bytes + 255) & ~(size_t)255;
        return p;
    };

    const size_t BHND = (size_t)B * H * N * DK;       // 4 Mi elems
    float* q        = (float*)alloc(BHND * 4);
    float* kbuf     = (float*)alloc(BHND * 4);
    float* vbuf     = (float*)alloc(BHND * 4);
    u16* cvAhi = (u16*)alloc((size_t)B * N * C * 2);  // x hi/lo
    u16* cvAlo = (u16*)alloc((size_t)B * N * C * 2);
    u16* cvBhi = (u16*)alloc((size_t)3 * C * C * 2);  // Wqkv hi/lo
    u16* cvBlo = (u16*)alloc((size_t)3 * C * C * 2);
    u16* cvWohi = (u16*)alloc((size_t)C * C * 2);     // Wout hi/lo
    u16* cvWolo = (u16*)alloc((size_t)C * C * 2);
    u16* aohi  = (u16*)alloc((size_t)B * N * C * 2);  // attn_out hi/lo
    u16* aolo  = (u16*)alloc((size_t)B * N * C * 2);
    u16* qhi   = (u16*)alloc(BHND * 2);
    u16* qlo   = (u16*)alloc(BHND * 2);
    u16* khi   = (u16*)alloc(BHND * 2);
    u16* klo   = (u16*)alloc(BHND * 2);
    u16* vthi  = (u16*)alloc(BHND * 2);
    u16* vtlo  = (u16*)alloc(BHND * 2);
    float* Mbuf     = (float*)alloc((size_t)BH * N * 4);
    float* rmaxbuf  = (float*)alloc((size_t)BH * N * 4);
    float* Mdot     = (float*)alloc((size_t)BH * N * 4);
    int*   keep     = (int*)  alloc((size_t)BH * N * 4);
    int*   inv      = (int*)  alloc((size_t)BH * N * 4);
    int*   kidx     = (int*)  alloc((size_t)BH * NTOP * 4);
    float* partbuf  = (float*)alloc((size_t)2 * BH * CSEG * DK * 4);
    float* thrbuf   = (float*)alloc((size_t)BH * 4);
    int*   cntbuf   = (int*)  alloc((size_t)BH * 4);
    int*   bandbuf  = (int*)  alloc((size_t)BH * BAND_CAP * 4);
    float* part_o   = (float*)alloc((size_t)2 * BH * NTOP * DK * 4);  // 8 MB
    float* part_l   = (float*)alloc((size_t)2 * BH * NTOP * 4);

    const int nX = B * N * C;        // 4M

    // 1. convert x, Wqkv, Wout to bf16 hi/lo (one launch, 8192 blocks)
    convert_hilo3<<<8192, 256, 0, stream>>>(
        x, Wqkv, Wout, cvAhi, cvAlo, cvBhi, cvBlo, cvWohi, cvWolo);

    // 2. QKV projection (2D grid — r9/r12-verified config)
    gemm_mfma<0><<<dim3(3 * C / 128, (B * N) / 128), 256, 0, stream>>>(
        cvAhi, cvAlo, cvBhi, cvBlo, bqkv, nullptr, q, kbuf, vbuf, C);

    // 3. convert q,k hi/lo (one launch); v transposed hi/lo
    convert_hilo2<<<dim3(nX / 1024, 2), 256, 0, stream>>>(
        q, kbuf, qhi, qlo, khi, klo, nX);
    convert_hilo_T<<<dim3(N / 64, BH), 256, 0, stream>>>(vbuf, vthi, vtlo);

    // 4. column sums of v and k (partials only; finals reduced in consumers)
    colsum_part2<<<dim3(CSEG, BH, 2), 256, 0, stream>>>(vbuf, kbuf, partbuf);

    // 5. mean term per row: Mdot = q . kmean (kmean reduced in-block)
    qdot_kernel<<<dim3(N / 256, BH), 256, 0, stream>>>(q, partbuf, Mdot);

    // 6. MFMA approximate row max -> M, rowmax (2D grid)
    row_stats_mfma<<<dim3(N / 128, BH), 256, 0, stream>>>(
        qhi, qlo, khi, klo, Mdot, Mbuf, rmaxbuf);

    // 7. selection: thr (+cnt init) -> classify -> fp64 refine -> finalize(+inv)
    topk_thr<<<dim3(N / 256, BH), 256, 0, stream>>>(Mbuf, thrbuf, cntbuf);
    band_classify<<<dim3(N / 256, BH), 256, 0, stream>>>(Mbuf, thrbuf, cntbuf, bandbuf, keep);
    refine_kernel<<<dim3(32, BH), 256, 0, stream>>>(q, kbuf, cntbuf, bandbuf, Mbuf);
    band_finalize<<<BH, 256, 0, stream>>>(Mbuf, cntbuf, bandbuf, keep, kidx, inv);

    // 8. split-K MFMA attention (partials) + fused epilogue (merge + vmean +
    //    direct bf16 hi/lo output)
    attn_mfma<<<512, 256, 0, stream>>>(
        qhi, qlo, khi, klo, vthi, vtlo, rmaxbuf, kidx, part_o, part_l);
    attn_epilogue<<<dim3(16, BH), 256, 0, stream>>>(
        part_o, part_l, keep, inv, partbuf, aohi, aolo);

    // 9. Output projection (2D grid) — consumes epilogue's hi/lo directly
    gemm_mfma<1><<<dim3(C / 128, (B * N) / 128), 256, 0, stream>>>(
        aohi, aolo, cvWohi, cvWolo, bout, out, nullptr, nullptr, nullptr, C);
}